// Round 4
// baseline (356.137 us; speedup 1.0000x reference)
//
#include <hip/hip_runtime.h>
#include <hip/hip_bf16.h>

typedef unsigned short u16;
typedef short bf16x8 __attribute__((ext_vector_type(8)));
typedef float f32x4 __attribute__((ext_vector_type(4)));

#define NB 8
#define NT 1024
#define ND 512
#define KSEL 307
#define WIN 144   // 64 t-rows + 2*40 halo

__device__ __forceinline__ float bf2f(u16 u){
  union { unsigned int i; float f; } c; c.i = ((unsigned int)u) << 16; return c.f;
}
__device__ __forceinline__ u16 f2bf(float f){
  __hip_bfloat16 h = __float2bfloat16(f);
  u16 u; __builtin_memcpy(&u, &h, 2); return u;
}

// ---------- canonicalize x -> xb (bf16) for the MFMA A-operand
__global__ void k_convert_x(const float* __restrict__ x, u16* __restrict__ xb){
  int i0 = (blockIdx.x * 256 + threadIdx.x) * 4;
#pragma unroll
  for (int j = 0; j < 4; j++){
    int i = i0 + j;
    xb[i] = f2bf(x[i]);
  }
}

// ---------- WcatT[c][d] = W[h=c>>6][d][f=c&63];  W2T[n][k] = W2[k][n]  (bf16)
__global__ void k_convert_w(const float* __restrict__ W, const float* __restrict__ W2,
                            u16* __restrict__ WcatT, u16* __restrict__ W2T){
  int idx = blockIdx.x * 256 + threadIdx.x;          // 0 .. 524287
  if (idx < 262144){
    int c = idx >> 9, d = idx & 511;
    int src = ((c >> 6) << 15) | (d << 6) | (c & 63);
    WcatT[idx] = f2bf(W[src]);
  } else {
    int i = idx - 262144;
    int n = i >> 9, k = i & 511;
    W2T[i] = f2bf(W2[(k << 9) | n]);
  }
}

// ---------- row magnitudes: mags[b*T+t] = ||x[b,t,:]||_2
__global__ void k_mags(const float* __restrict__ x, float* __restrict__ mags){
  int row = blockIdx.x;              // 8192
  int l = threadIdx.x;               // 64
  const float* xr = x + row * ND;
  float s = 0.f;
#pragma unroll
  for (int i = 0; i < 8; i++){ float v = xr[l + 64*i]; s += v*v; }
#pragma unroll
  for (int off = 32; off; off >>= 1) s += __shfl_xor(s, off, 64);
  if (l == 0) mags[row] = sqrtf(s);
}

// ---------- exact top-k selection by ranking (ties -> lower index wins)
__global__ void k_select(const float* __restrict__ mags, int* __restrict__ sel){
  __shared__ float sm[NT];
  int b = blockIdx.x, t = threadIdx.x;
  float m = mags[b * NT + t];
  sm[t] = m;
  __syncthreads();
  int cnt = 0;
  for (int s = 0; s < NT; s++){
    float v = sm[s];
    cnt += (v > m) || (v == m && s < t);
  }
  sel[b * NT + t] = (cnt < KSEL) ? 1 : 0;
}

// ---------- MFMA bf16 GEMM: Whb[8192,512](bf16) = xb @ Wcat ; Bt = Wcat^T [n][k]
__launch_bounds__(256)
__global__ void k_gemm_wh(const u16* __restrict__ A, const u16* __restrict__ Bt,
                          u16* __restrict__ C){
  __shared__ u16 As[128 * 40];
  __shared__ u16 Bs[128 * 40];
  int m0 = blockIdx.x * 128, n0 = blockIdx.y * 128;
  int tid = threadIdx.x;
  int wv = tid >> 6, lane = tid & 63;
  int wr = wv & 1, wc = wv >> 1;
  int quad = lane >> 4, lr = lane & 15;
  f32x4 acc[4][4] = {};
  for (int kt = 0; kt < 512; kt += 32){
    __syncthreads();
#pragma unroll
    for (int i = 0; i < 2; i++){
      int e = tid * 8 + i * 2048;
      int r = e >> 5, c = e & 31;
      *(bf16x8*)&As[r*40 + c] = *(const bf16x8*)&A[(m0 + r) * 512 + kt + c];
      *(bf16x8*)&Bs[r*40 + c] = *(const bf16x8*)&Bt[(n0 + r) * 512 + kt + c];
    }
    __syncthreads();
    bf16x8 af[4], bfr[4];
#pragma unroll
    for (int i = 0; i < 4; i++){
      af[i]  = *(const bf16x8*)&As[(wr*64 + i*16 + lr)*40 + quad*8];
      bfr[i] = *(const bf16x8*)&Bs[(wc*64 + i*16 + lr)*40 + quad*8];
    }
#pragma unroll
    for (int mi = 0; mi < 4; mi++)
#pragma unroll
      for (int ni = 0; ni < 4; ni++)
        acc[mi][ni] = __builtin_amdgcn_mfma_f32_16x16x32_bf16(af[mi], bfr[ni], acc[mi][ni], 0, 0, 0);
  }
#pragma unroll
  for (int mi = 0; mi < 4; mi++)
#pragma unroll
    for (int ni = 0; ni < 4; ni++){
      int rg = m0 + wr*64 + mi*16 + quad*4;
      int cg = n0 + wc*64 + ni*16 + lr;
#pragma unroll
      for (int r = 0; r < 4; r++) C[(rg + r) * 512 + cg] = f2bf(acc[mi][ni][r]);
    }
}

// ---------- GEMM2: Y(f32) = tmpb @ W2 + x + b2
__launch_bounds__(256)
__global__ void k_gemm2(const u16* __restrict__ A, const u16* __restrict__ Bt,
                        const float* __restrict__ xres, const float* __restrict__ b2,
                        float* __restrict__ Y){
  __shared__ u16 As[128 * 40];
  __shared__ u16 Bs[128 * 40];
  int m0 = blockIdx.x * 128, n0 = blockIdx.y * 128;
  int tid = threadIdx.x;
  int wv = tid >> 6, lane = tid & 63;
  int wr = wv & 1, wc = wv >> 1;
  int quad = lane >> 4, lr = lane & 15;
  f32x4 acc[4][4] = {};
  for (int kt = 0; kt < 512; kt += 32){
    __syncthreads();
#pragma unroll
    for (int i = 0; i < 2; i++){
      int e = tid * 8 + i * 2048;
      int r = e >> 5, c = e & 31;
      *(bf16x8*)&As[r*40 + c] = *(const bf16x8*)&A[(m0 + r) * 512 + kt + c];
      *(bf16x8*)&Bs[r*40 + c] = *(const bf16x8*)&Bt[(n0 + r) * 512 + kt + c];
    }
    __syncthreads();
    bf16x8 af[4], bfr[4];
#pragma unroll
    for (int i = 0; i < 4; i++){
      af[i]  = *(const bf16x8*)&As[(wr*64 + i*16 + lr)*40 + quad*8];
      bfr[i] = *(const bf16x8*)&Bs[(wc*64 + i*16 + lr)*40 + quad*8];
    }
#pragma unroll
    for (int mi = 0; mi < 4; mi++)
#pragma unroll
      for (int ni = 0; ni < 4; ni++)
        acc[mi][ni] = __builtin_amdgcn_mfma_f32_16x16x32_bf16(af[mi], bfr[ni], acc[mi][ni], 0, 0, 0);
  }
#pragma unroll
  for (int mi = 0; mi < 4; mi++)
#pragma unroll
    for (int ni = 0; ni < 4; ni++){
      int rg = m0 + wr*64 + mi*16 + quad*4;
      int cg = n0 + wc*64 + ni*16 + lr;
#pragma unroll
      for (int r = 0; r < 4; r++){
        int idx = (rg + r) * 512 + cg;
        Y[idx] = acc[mi][ni][r] + xres[idx] + b2[cg];
      }
    }
}

// ---------- e_src/e_dst: per (b,t) wave, 8 heads reduced via shuffles
__global__ void k_edge(const u16* __restrict__ Whb, const float* __restrict__ asf,
                       const float* __restrict__ adf, float* __restrict__ es,
                       float* __restrict__ ed){
  int wid = threadIdx.x >> 6, lane = threadIdx.x & 63;
  int row = blockIdx.x * 4 + wid;     // b*T + t
  const u16* wr = Whb + row * ND;
  float vs[8], vd[8];
#pragma unroll
  for (int h = 0; h < 8; h++){
    float w = bf2f(wr[h * 64 + lane]);
    vs[h] = w * asf[h * 64 + lane];
    vd[h] = w * adf[h * 64 + lane];
  }
#pragma unroll
  for (int off = 32; off; off >>= 1)
#pragma unroll
    for (int h = 0; h < 8; h++){
      vs[h] += __shfl_xor(vs[h], off, 64);
      vd[h] += __shfl_xor(vd[h], off, 64);
    }
  if (lane == 0){
    int b = row >> 10, t = row & 1023;
#pragma unroll
    for (int h = 0; h < 8; h++){
      es[(b * 8 + h) * NT + t] = vs[h];
      ed[(b * 8 + h) * NT + t] = vd[h];
    }
  }
}

// ---------- banded masked attention + elu + signed-sqrt -> t2b (bf16)
__launch_bounds__(256)
__global__ void k_attn(const u16* __restrict__ Whb, const float* __restrict__ es,
                       const float* __restrict__ ed, const int* __restrict__ sel,
                       u16* __restrict__ t2b){
  __shared__ float Vw[WIN * 64];
  __shared__ float wTab[64 * 81];
  __shared__ float edw[WIN];
  __shared__ int   selw[WIN];
  __shared__ float esw[64];
  int bh = blockIdx.x;                  // 64 = b*8+h
  int b = bh >> 3, h = bh & 7;
  int t0 = blockIdx.y * 64;
  int tid = threadIdx.x;
  int s_base = t0 - 40;
  for (int i = tid; i < WIN; i += 256){
    int s = s_base + i;
    bool ok = (s >= 0 && s < NT);
    edw[i]  = ok ? ed[(b * 8 + h) * NT + s] : 0.f;
    selw[i] = ok ? sel[b * NT + s] : 0;
  }
  if (tid < 64) esw[tid] = es[(b * 8 + h) * NT + t0 + tid];
  for (int i = tid; i < WIN * 64; i += 256){
    int r = i >> 6, f = i & 63;
    int s = s_base + r;
    if (s >= 0 && s < NT) Vw[i] = bf2f(Whb[(b * NT + s) * ND + h * 64 + f]);
  }
  __syncthreads();
  // weight table  w[tl][j],  s = (t0+tl) - 40 + j,  window row r = tl + j
  for (int idx = tid; idx < 64 * 81; idx += 256){
    int tl = idx / 81, j = idx - tl * 81;
    int r = tl + j;
    int s = s_base + r;
    float w = 0.f;
    if (s >= 0 && s < NT && (selw[tl + 40] | selw[r])){
      float v = esw[tl] + edw[r];
      v = v > 0.f ? v : 0.2f * v;       // LeakyReLU(0.2)
      v = fminf(v, 60.f);               // inert clamp
      w = __expf(v);
    }
    wTab[idx] = w;
  }
  __syncthreads();
  int wv = tid >> 6, lane = tid & 63;
#pragma unroll 1
  for (int i = 0; i < 16; i++){
    int tl = wv * 16 + i;
    int t = t0 + tl;
    int jlo = max(0, 40 - t);
    int jhi = min(80, 1063 - t);
    float acc = 0.f, sw = 0.f;
    const float* wrow = &wTab[tl * 81];
    for (int j = jlo; j <= jhi; j++){
      float w = wrow[j];
      sw += w;
      acc = fmaf(w, Vw[(tl + j) * 64 + lane], acc);
    }
    float hp = acc / (sw > 0.f ? sw : 1.f);
    hp = hp > 0.f ? hp : (__expf(hp) - 1.f);                  // ELU
    float o = hp >= 0.f ? sqrtf(hp) : -sqrtf(-hp);            // signed sqrt
    t2b[(b * NT + t) * ND + h * 64 + lane] = f2bf(o);
  }
}

__global__ void k_zero(float* __restrict__ p){
  int i = blockIdx.x * 256 + threadIdx.x;
  if (i < NB * ND) p[i] = 0.f;
}

// ---------- column (over T) sum of squares
__global__ void k_colsum(const u16* __restrict__ t2b, float* __restrict__ cn){
  int b = blockIdx.y, tc = blockIdx.x;   // 32 chunks of 32 rows
  int d = threadIdx.x;
#pragma unroll
  for (int half = 0; half < 2; half++){
    int dd = d + half * 256;
    float s = 0.f;
    for (int i = 0; i < 32; i++){
      float v = bf2f(t2b[(b * NT + tc * 32 + i) * ND + dd]);
      s += v * v;
    }
    atomicAdd(&cn[b * ND + dd], s);
  }
}

// ---------- tmp / max(||tmp||_T, eps) -> bf16
__global__ void k_normalize(const u16* __restrict__ t2b, const float* __restrict__ cn,
                            u16* __restrict__ tmpb){
  int idx = (blockIdx.x * 256 + threadIdx.x) * 8;
  int b = idx >> 19;                      // 1024*512 per batch
#pragma unroll
  for (int i = 0; i < 8; i++){
    int id = idx + i;
    int d = id & 511;
    float nv = sqrtf(cn[b * ND + d]);
    float v = bf2f(t2b[id]) / fmaxf(nv, 1e-12f);
    tmpb[id] = f2bf(v);
  }
}

// ---------- per-row LN stats
__global__ void k_rowstats(const float* __restrict__ Y, float* __restrict__ mu,
                           float* __restrict__ rstd){
  int wid = threadIdx.x >> 6, lane = threadIdx.x & 63;
  int row = blockIdx.x * 4 + wid;
  const float* yr = Y + row * ND;
  float s = 0.f, q = 0.f;
#pragma unroll
  for (int i = 0; i < 8; i++){ float v = yr[lane + 64*i]; s += v; q += v*v; }
#pragma unroll
  for (int off = 32; off; off >>= 1){ s += __shfl_xor(s, off, 64); q += __shfl_xor(q, off, 64); }
  if (lane == 0){
    float m = s * (1.f/512.f);
    float var = q * (1.f/512.f) - m * m;
    mu[row] = m;
    rstd[row] = 1.f / sqrtf(var + 1e-5f);
  }
}

// ---------- apply LN + transpose to out[b, d, t] (f32 — reference output dtype)
__global__ void k_out(const float* __restrict__ Y, const float* __restrict__ mu,
                      const float* __restrict__ rstd, const float* __restrict__ g,
                      const float* __restrict__ bb, float* __restrict__ out){
  __shared__ float tile[64 * 65];
  int t0 = blockIdx.x * 64, d0 = blockIdx.y * 64, b = blockIdx.z;
  int tid = threadIdx.x;
  int j = tid & 63, i0 = tid >> 6;
#pragma unroll
  for (int k = 0; k < 16; k++){
    int i = i0 + k * 4;
    int row = b * NT + t0 + i;
    float v = (Y[row * ND + d0 + j] - mu[row]) * rstd[row] * g[d0 + j] + bb[d0 + j];
    tile[i * 65 + j] = v;
  }
  __syncthreads();
#pragma unroll
  for (int k = 0; k < 16; k++){
    int jj = i0 + k * 4;   // d-local
    int ii = j;            // t-local
    out[(b * ND + d0 + jj) * NT + t0 + ii] = tile[ii * 65 + jj];
  }
}

extern "C" void kernel_launch(void* const* d_in, const int* in_sizes, int n_in,
                              void* d_out, int out_size, void* d_ws, size_t ws_size,
                              hipStream_t stream) {
  (void)in_sizes; (void)n_in; (void)out_size; (void)ws_size;
  const float* x     = (const float*)d_in[0];
  const float* W     = (const float*)d_in[1];
  const float* a_src = (const float*)d_in[2];
  const float* a_dst = (const float*)d_in[3];
  const float* W2    = (const float*)d_in[4];
  const float* b2    = (const float*)d_in[5];
  const float* ln_g  = (const float*)d_in[6];
  const float* ln_b  = (const float*)d_in[7];
  char* ws = (char*)d_ws;
  // compact layout: peak usage ~26 MB
  int*   sel   = (int*)  (ws + 256);
  float* mags  = (float*)(ws + 33024);
  u16*   WcatT = (u16*)  (ws + 65792);
  u16*   W2T   = (u16*)  (ws + 590080);
  float* es    = (float*)(ws + 1124608);
  float* ed    = (float*)(ws + 1386752);
  float* cn    = (float*)(ws + 1648896);
  float* mu    = (float*)(ws + 1665280);
  float* rstd  = (float*)(ws + 1698048);
  u16*   xb    = (u16*)  (ws + 2097152);   // region A (8 MB); tmpb aliases (xb dead after k_gemm_wh)
  u16*   Whb   = (u16*)  (ws + 10485760);  // region B (8 MB)
  u16*   t2b   = (u16*)  (ws + 18874368);  // region C (8 MB)
  u16*   tmpb  = xb;
  float* Y     = (float*)(ws + 10485760);  // overlays B+C (16 MB); written after Whb/t2b dead
  float* out   = (float*)d_out;

  k_convert_x<<<4096, 256, 0, stream>>>(x, xb);
  k_convert_w<<<2048, 256, 0, stream>>>(W, W2, WcatT, W2T);
  k_mags     <<<8192, 64, 0, stream>>>(x, mags);
  k_select   <<<NB, 1024, 0, stream>>>(mags, sel);
  k_gemm_wh  <<<dim3(64, 4), 256, 0, stream>>>(xb, WcatT, Whb);
  k_edge     <<<2048, 256, 0, stream>>>(Whb, a_src, a_dst, es, ed);
  k_attn     <<<dim3(64, 16), 256, 0, stream>>>(Whb, es, ed, sel, t2b);
  k_zero     <<<16, 256, 0, stream>>>(cn);
  k_colsum   <<<dim3(32, 8), 256, 0, stream>>>(t2b, cn);
  k_normalize<<<2048, 256, 0, stream>>>(t2b, cn, tmpb);
  k_gemm2    <<<dim3(64, 4), 256, 0, stream>>>(tmpb, W2T, x, b2, Y);
  k_rowstats <<<2048, 256, 0, stream>>>(Y, mu, rstd);
  k_out      <<<dim3(16, 8, 8), 256, 0, stream>>>(Y, mu, rstd, ln_g, ln_b, out);
}

// Round 5
// 213.990 us; speedup vs baseline: 1.6643x; 1.6643x over previous
//
#include <hip/hip_runtime.h>
#include <hip/hip_bf16.h>

typedef unsigned short u16;
typedef short bf16x8 __attribute__((ext_vector_type(8)));
typedef float f32x4 __attribute__((ext_vector_type(4)));
typedef int   i32x4 __attribute__((ext_vector_type(4)));

#define NB 8
#define NT 1024
#define ND 512
#define KSEL 307
#define PSTR 152   // P LDS row stride (elems); 304 B = 19*16 ✓ aligned, 2-way-only conflicts

__device__ __forceinline__ float bf2f(u16 u){
  union { unsigned int i; float f; } c; c.i = ((unsigned int)u) << 16; return c.f;
}
__device__ __forceinline__ u16 f2bf(float f){
  __hip_bfloat16 h = __float2bfloat16(f);
  u16 u; __builtin_memcpy(&u, &h, 2); return u;
}

// ---------- WcatT[c][d] = W[h=c>>6][d][f=c&63];  W2T[n][k] = W2[k][n]  (bf16)
__global__ void k_convert_w(const float* __restrict__ W, const float* __restrict__ W2,
                            u16* __restrict__ WcatT, u16* __restrict__ W2T){
  int idx = blockIdx.x * 256 + threadIdx.x;          // 0 .. 524287
  if (idx < 262144){
    int c = idx >> 9, d = idx & 511;
    int src = ((c >> 6) << 15) | (d << 6) | (c & 63);
    WcatT[idx] = f2bf(W[src]);
  } else {
    int i = idx - 262144;
    int n = i >> 9, k = i & 511;
    W2T[i] = f2bf(W2[(k << 9) | n]);
  }
}

// ---------- row magnitudes: mags[b*T+t] = ||x[b,t,:]||_2
__global__ void k_mags(const float* __restrict__ x, float* __restrict__ mags){
  int row = blockIdx.x;              // 8192
  int l = threadIdx.x;               // 64
  const float* xr = x + row * ND;
  float s = 0.f;
#pragma unroll
  for (int i = 0; i < 8; i++){ float v = xr[l + 64*i]; s += v*v; }
#pragma unroll
  for (int off = 32; off; off >>= 1) s += __shfl_xor(s, off, 64);
  if (l == 0) mags[row] = sqrtf(s);
}

// ---------- exact top-k selection by ranking (ties -> lower index wins)
__global__ void k_select(const float* __restrict__ mags, int* __restrict__ sel){
  __shared__ float sm[NT];
  int b = blockIdx.x, t = threadIdx.x;
  float m = mags[b * NT + t];
  sm[t] = m;
  __syncthreads();
  int cnt = 0;
  for (int s = 0; s < NT; s++){
    float v = sm[s];
    cnt += (v > m) || (v == m && s < t);
  }
  sel[b * NT + t] = (cnt < KSEL) ? 1 : 0;
}

// ---------- MFMA bf16 GEMM: Whb[8192,512](bf16) = bf16(x) @ Wcat ; Bt = Wcat^T [n][k]
__launch_bounds__(256)
__global__ void k_gemm_wh(const float* __restrict__ x, const u16* __restrict__ Bt,
                          u16* __restrict__ C){
  __shared__ u16 As[128 * 40];
  __shared__ u16 Bs[128 * 40];
  int m0 = blockIdx.x * 128, n0 = blockIdx.y * 128;
  int tid = threadIdx.x;
  int wv = tid >> 6, lane = tid & 63;
  int wr = wv & 1, wc = wv >> 1;
  int quad = lane >> 4, lr = lane & 15;
  f32x4 acc[4][4] = {};
  for (int kt = 0; kt < 512; kt += 32){
    __syncthreads();
#pragma unroll
    for (int i = 0; i < 2; i++){
      int e = tid * 8 + i * 2048;
      int r = e >> 5, c = e & 31;
      // A: load f32 x, convert to bf16 inline
      const float* xa = &x[(m0 + r) * 512 + kt + c];
      f32x4 u0 = *(const f32x4*)xa;
      f32x4 u1 = *(const f32x4*)(xa + 4);
      u16 pk[8];
#pragma unroll
      for (int q = 0; q < 4; q++){ pk[q] = f2bf(u0[q]); pk[4+q] = f2bf(u1[q]); }
      *(bf16x8*)&As[r*40 + c] = *(const bf16x8*)pk;
      *(bf16x8*)&Bs[r*40 + c] = *(const bf16x8*)&Bt[(n0 + r) * 512 + kt + c];
    }
    __syncthreads();
    bf16x8 af[4], bfr[4];
#pragma unroll
    for (int i = 0; i < 4; i++){
      af[i]  = *(const bf16x8*)&As[(wr*64 + i*16 + lr)*40 + quad*8];
      bfr[i] = *(const bf16x8*)&Bs[(wc*64 + i*16 + lr)*40 + quad*8];
    }
#pragma unroll
    for (int mi = 0; mi < 4; mi++)
#pragma unroll
      for (int ni = 0; ni < 4; ni++)
        acc[mi][ni] = __builtin_amdgcn_mfma_f32_16x16x32_bf16(af[mi], bfr[ni], acc[mi][ni], 0, 0, 0);
  }
#pragma unroll
  for (int mi = 0; mi < 4; mi++)
#pragma unroll
    for (int ni = 0; ni < 4; ni++){
      int rg = m0 + wr*64 + mi*16 + quad*4;
      int cg = n0 + wc*64 + ni*16 + lr;
#pragma unroll
      for (int r = 0; r < 4; r++) C[(rg + r) * 512 + cg] = f2bf(acc[mi][ni][r]);
    }
}

// ---------- transpose Whb[b][t][h*64+f] -> WhT[(b*8+h)*64+f][t]
__global__ void k_transpose(const u16* __restrict__ Whb, u16* __restrict__ WhT){
  __shared__ u16 tile[64 * 68];
  int t0 = blockIdx.x * 64;          // 16 t-tiles
  int bh = blockIdx.y;               // 64
  int b = bh >> 3, h = bh & 7;
  int tid = threadIdx.x;
  int j = tid & 63, i0 = tid >> 6;
#pragma unroll
  for (int k = 0; k < 16; k++){
    int i = i0 + k * 4;
    tile[i * 68 + j] = Whb[(b * NT + t0 + i) * 512 + h * 64 + j];
  }
  __syncthreads();
#pragma unroll
  for (int k = 0; k < 16; k++){
    int f = i0 + k * 4;
    WhT[(bh * 64 + f) * NT + t0 + j] = tile[j * 68 + f];
  }
}

// ---------- e_src/e_dst from WhT (coalesced over t)
__global__ void k_edge(const u16* __restrict__ WhT, const float* __restrict__ a_src,
                       const float* __restrict__ a_dst, float* __restrict__ es,
                       float* __restrict__ ed){
  int t = blockIdx.x * 256 + threadIdx.x;
  int bh = blockIdx.y;
  int h = bh & 7;
  const u16* base = WhT + (bh * 64) * NT + t;
  float se = 0.f, de = 0.f;
#pragma unroll
  for (int f = 0; f < 64; f++){
    float w = bf2f(base[f * NT]);
    se += w * a_src[h * 64 + f];
    de += w * a_dst[h * 64 + f];
  }
  es[bh * NT + t] = se;
  ed[bh * NT + t] = de;
}

// ---------- banded masked attention via MFMA + elu + signed-sqrt -> t2b (bf16)
__launch_bounds__(256)
__global__ void k_attn(const u16* __restrict__ WhT, const float* __restrict__ es,
                       const float* __restrict__ ed, const int* __restrict__ sel,
                       u16* __restrict__ t2b){
  __shared__ u16 P[64 * PSTR];       // 19456 B, band weights (bf16)
  __shared__ float edw[144];
  __shared__ int   selw[144];
  __shared__ float esw[64];
  __shared__ float swv[64];
  int bh = blockIdx.x;               // b*8+h
  int b = bh >> 3;
  int t0 = blockIdx.y * 64;
  int tid = threadIdx.x;
  int wv = tid >> 6, lane = tid & 63;
  int quad = lane >> 4, lr = lane & 15;
  int s_base = t0 - 40;
  // stage aux (shared across waves)
  for (int i = tid; i < 144; i += 256){
    int s = s_base + i;
    bool ok = (s >= 0 && s < NT);
    edw[i]  = ok ? ed[bh * NT + s] : 0.f;
    selw[i] = ok ? sel[b * NT + s] : 0;
  }
  if (tid < 64) esw[tid] = es[bh * NT + t0 + tid];
  // zero this wave's 16 rows of P (wave-local; 19 int4-chunks per 304B row)
  {
    i32x4 z = {};
    for (int i = lane; i < 304; i += 64){
      int r16 = i / 19, c16 = i - r16 * 19;
      *(i32x4*)&P[(16*wv + r16) * PSTR + c16 * 8] = z;
    }
  }
  __syncthreads();
  // generate band weights for this wave's rows; 4 threads per row
  {
    int tl = 16*wv + (lane >> 2);
    int q = lane & 3;
    float e_t = esw[tl];
    int sel_t = selw[tl + 40];
    float part = 0.f;
    for (int j = q; j <= 80; j += 4){
      int sw = tl + j;
      int s = s_base + sw;
      float w = 0.f;
      if (s >= 0 && s < NT && (sel_t | selw[sw])){
        float v = e_t + edw[sw];
        v = v > 0.f ? v : 0.2f * v;      // LeakyReLU(0.2)
        v = fminf(v, 60.f);
        w = bf2f(f2bf(__expf(v)));       // round once; use same value in num & denom
      }
      part += w;
      if (w != 0.f) P[tl * PSTR + sw] = f2bf(w);
    }
    part += __shfl_xor(part, 1, 64);
    part += __shfl_xor(part, 2, 64);
    if (q == 0) swv[tl] = part;
  }
  // MFMA: O(16x64) = P_tile(16x96) * V(96x64); V read from global WhT (B-frag layout)
  f32x4 acc[4] = {};
  const u16* vbase = WhT + (bh * 64) * NT;
#pragma unroll
  for (int ks = 0; ks < 96; ks += 32){
    bf16x8 afr = *(const bf16x8*)&P[(16*wv + lr) * PSTR + 16*wv + ks + quad*8];
    int tb = s_base + 16*wv + ks + quad*8;      // multiple of 8 -> chunk fully in/out
    bool ok = (tb >= 0) && (tb < NT);
    bf16x8 zf = {};
#pragma unroll
    for (int jn = 0; jn < 4; jn++){
      bf16x8 bfr = ok ? *(const bf16x8*)&vbase[(16*jn + lr) * NT + tb] : zf;
      acc[jn] = __builtin_amdgcn_mfma_f32_16x16x32_bf16(afr, bfr, acc[jn], 0, 0, 0);
    }
  }
  // epilogue: softmax divide, ELU, signed sqrt, store
#pragma unroll
  for (int jn = 0; jn < 4; jn++){
#pragma unroll
    for (int r = 0; r < 4; r++){
      int t_loc = 16*wv + quad*4 + r;
      float sw_ = swv[t_loc];
      float hp = acc[jn][r] / (sw_ > 0.f ? sw_ : 1.f);
      hp = hp > 0.f ? hp : (__expf(hp) - 1.f);
      float o = hp >= 0.f ? sqrtf(hp) : -sqrtf(-hp);
      t2b[(b * NT + t0 + t_loc) * ND + (bh & 7) * 64 + 16*jn + lr] = f2bf(o);
    }
  }
}

// ---------- column (over T) sum of squares
__global__ void k_colsum(const u16* __restrict__ t2b, float* __restrict__ cn){
  int b = blockIdx.y, tc = blockIdx.x;   // 32 chunks of 32 rows
  int d = threadIdx.x;
#pragma unroll
  for (int half = 0; half < 2; half++){
    int dd = d + half * 256;
    float s = 0.f;
    for (int i = 0; i < 32; i++){
      float v = bf2f(t2b[(b * NT + tc * 32 + i) * ND + dd]);
      s += v * v;
    }
    atomicAdd(&cn[b * ND + dd], s);
  }
}

// ---------- tmp / max(||tmp||_T, eps) -> bf16 (in-place on t2b region)
__global__ void k_normalize(const u16* __restrict__ t2b, const float* __restrict__ cn,
                            u16* __restrict__ tmpb){
  int idx = (blockIdx.x * 256 + threadIdx.x) * 8;
  int b = idx >> 19;
#pragma unroll
  for (int i = 0; i < 8; i++){
    int id = idx + i;
    int d = id & 511;
    float nv = sqrtf(cn[b * ND + d]);
    float v = bf2f(t2b[id]) / fmaxf(nv, 1e-12f);
    tmpb[id] = f2bf(v);
  }
}

// ---------- GEMM2: Y(f32) = tmpb @ W2 + x + b2
__launch_bounds__(256)
__global__ void k_gemm2(const u16* __restrict__ A, const u16* __restrict__ Bt,
                        const float* __restrict__ xres, const float* __restrict__ b2,
                        float* __restrict__ Y){
  __shared__ u16 As[128 * 40];
  __shared__ u16 Bs[128 * 40];
  int m0 = blockIdx.x * 128, n0 = blockIdx.y * 128;
  int tid = threadIdx.x;
  int wv = tid >> 6, lane = tid & 63;
  int wr = wv & 1, wc = wv >> 1;
  int quad = lane >> 4, lr = lane & 15;
  f32x4 acc[4][4] = {};
  for (int kt = 0; kt < 512; kt += 32){
    __syncthreads();
#pragma unroll
    for (int i = 0; i < 2; i++){
      int e = tid * 8 + i * 2048;
      int r = e >> 5, c = e & 31;
      *(bf16x8*)&As[r*40 + c] = *(const bf16x8*)&A[(m0 + r) * 512 + kt + c];
      *(bf16x8*)&Bs[r*40 + c] = *(const bf16x8*)&Bt[(n0 + r) * 512 + kt + c];
    }
    __syncthreads();
    bf16x8 af[4], bfr[4];
#pragma unroll
    for (int i = 0; i < 4; i++){
      af[i]  = *(const bf16x8*)&As[(wr*64 + i*16 + lr)*40 + quad*8];
      bfr[i] = *(const bf16x8*)&Bs[(wc*64 + i*16 + lr)*40 + quad*8];
    }
#pragma unroll
    for (int mi = 0; mi < 4; mi++)
#pragma unroll
      for (int ni = 0; ni < 4; ni++)
        acc[mi][ni] = __builtin_amdgcn_mfma_f32_16x16x32_bf16(af[mi], bfr[ni], acc[mi][ni], 0, 0, 0);
  }
#pragma unroll
  for (int mi = 0; mi < 4; mi++)
#pragma unroll
    for (int ni = 0; ni < 4; ni++){
      int rg = m0 + wr*64 + mi*16 + quad*4;
      int cg = n0 + wc*64 + ni*16 + lr;
#pragma unroll
      for (int r = 0; r < 4; r++){
        int idx = (rg + r) * 512 + cg;
        Y[idx] = acc[mi][ni][r] + xres[idx] + b2[cg];
      }
    }
}

// ---------- per-row LN stats
__global__ void k_rowstats(const float* __restrict__ Y, float* __restrict__ mu,
                           float* __restrict__ rstd){
  int wid = threadIdx.x >> 6, lane = threadIdx.x & 63;
  int row = blockIdx.x * 4 + wid;
  const float* yr = Y + row * ND;
  float s = 0.f, q = 0.f;
#pragma unroll
  for (int i = 0; i < 8; i++){ float v = yr[lane + 64*i]; s += v; q += v*v; }
#pragma unroll
  for (int off = 32; off; off >>= 1){ s += __shfl_xor(s, off, 64); q += __shfl_xor(q, off, 64); }
  if (lane == 0){
    float m = s * (1.f/512.f);
    float var = q * (1.f/512.f) - m * m;
    mu[row] = m;
    rstd[row] = 1.f / sqrtf(var + 1e-5f);
  }
}

// ---------- apply LN + transpose to out[b, d, t] (f32)
__global__ void k_out(const float* __restrict__ Y, const float* __restrict__ mu,
                      const float* __restrict__ rstd, const float* __restrict__ g,
                      const float* __restrict__ bb, float* __restrict__ out){
  __shared__ float tile[64 * 65];
  int t0 = blockIdx.x * 64, d0 = blockIdx.y * 64, b = blockIdx.z;
  int tid = threadIdx.x;
  int j = tid & 63, i0 = tid >> 6;
#pragma unroll
  for (int k = 0; k < 16; k++){
    int i = i0 + k * 4;
    int row = b * NT + t0 + i;
    float v = (Y[row * ND + d0 + j] - mu[row]) * rstd[row] * g[d0 + j] + bb[d0 + j];
    tile[i * 65 + j] = v;
  }
  __syncthreads();
#pragma unroll
  for (int k = 0; k < 16; k++){
    int jj = i0 + k * 4;   // d-local
    int ii = j;            // t-local
    out[(b * ND + d0 + jj) * NT + t0 + ii] = tile[ii * 65 + jj];
  }
}

extern "C" void kernel_launch(void* const* d_in, const int* in_sizes, int n_in,
                              void* d_out, int out_size, void* d_ws, size_t ws_size,
                              hipStream_t stream) {
  (void)in_sizes; (void)n_in; (void)out_size; (void)ws_size;
  const float* x     = (const float*)d_in[0];
  const float* W     = (const float*)d_in[1];
  const float* a_src = (const float*)d_in[2];
  const float* a_dst = (const float*)d_in[3];
  const float* W2    = (const float*)d_in[4];
  const float* b2    = (const float*)d_in[5];
  const float* ln_g  = (const float*)d_in[6];
  const float* ln_b  = (const float*)d_in[7];
  char* ws = (char*)d_ws;
  // layout (26 MB peak, same footprint as the round-4 pass)
  int*   sel   = (int*)  (ws + 256);
  float* mags  = (float*)(ws + 33024);
  u16*   WcatT = (u16*)  (ws + 65792);
  u16*   W2T   = (u16*)  (ws + 590080);
  float* es    = (float*)(ws + 1124608);
  float* ed    = (float*)(ws + 1386752);
  float* cn    = (float*)(ws + 1648896);
  float* mu    = (float*)(ws + 1665280);
  float* rstd  = (float*)(ws + 1698048);
  u16*   Whb   = (u16*)  (ws + 2097152);   // region B (8 MB), dead after k_transpose
  u16*   WhT   = (u16*)  (ws + 10485760);  // region C (8 MB), dead after k_attn
  u16*   t2b   = (u16*)  (ws + 18874368);  // region D (8 MB); normalize in-place
  u16*   tmpb  = t2b;
  float* Y     = (float*)(ws + 2097152);   // overlays B+C (16 MB), written after both dead
  float* out   = (float*)d_out;

  k_mags     <<<8192, 64, 0, stream>>>(x, mags);
  k_select   <<<NB, 1024, 0, stream>>>(mags, sel);
  k_convert_w<<<2048, 256, 0, stream>>>(W, W2, WcatT, W2T);
  k_gemm_wh  <<<dim3(64, 4), 256, 0, stream>>>(x, WcatT, Whb);
  k_transpose<<<dim3(16, 64), 256, 0, stream>>>(Whb, WhT);
  k_edge     <<<dim3(4, 64), 256, 0, stream>>>(WhT, a_src, a_dst, es, ed);
  k_attn     <<<dim3(64, 16), 256, 0, stream>>>(WhT, es, ed, sel, t2b);
  hipMemsetAsync(cn, 0, NB * ND * sizeof(float), stream);
  k_colsum   <<<dim3(32, 8), 256, 0, stream>>>(t2b, cn);
  k_normalize<<<2048, 256, 0, stream>>>(t2b, cn, tmpb);
  k_gemm2    <<<dim3(64, 4), 256, 0, stream>>>(tmpb, W2T, x, b2, Y);
  k_rowstats <<<2048, 256, 0, stream>>>(Y, mu, rstd);
  k_out      <<<dim3(16, 8, 8), 256, 0, stream>>>(Y, mu, rstd, ln_g, ln_b, out);
}

// Round 6
// 179.538 us; speedup vs baseline: 1.9836x; 1.1919x over previous
//
#include <hip/hip_runtime.h>
#include <hip/hip_bf16.h>

typedef unsigned short u16;
typedef short bf16x8 __attribute__((ext_vector_type(8)));
typedef float f32x4 __attribute__((ext_vector_type(4)));
typedef int   i32x4 __attribute__((ext_vector_type(4)));

#define NB 8
#define NT 1024
#define ND 512
#define KSEL 307
#define PSTR 152   // attn P LDS row stride (elems)
#define TSTR 136   // gemm_wh transpose LDS row stride (elems); 272 B, 16B-aligned

__device__ __forceinline__ float bf2f(u16 u){
  union { unsigned int i; float f; } c; c.i = ((unsigned int)u) << 16; return c.f;
}
__device__ __forceinline__ u16 f2bf(float f){
  __hip_bfloat16 h = __float2bfloat16(f);
  u16 u; __builtin_memcpy(&u, &h, 2); return u;
}

// ---------- WcatT[c][d] = W[h=c>>6][d][f=c&63];  W2T[n][k] = W2[k][n]  (bf16)
__global__ void k_convert_w(const float* __restrict__ W, const float* __restrict__ W2,
                            u16* __restrict__ WcatT, u16* __restrict__ W2T){
  int idx = blockIdx.x * 256 + threadIdx.x;          // 0 .. 524287
  if (idx < 262144){
    int c = idx >> 9, d = idx & 511;
    int src = ((c >> 6) << 15) | (d << 6) | (c & 63);
    WcatT[idx] = f2bf(W[src]);
  } else {
    int i = idx - 262144;
    int n = i >> 9, k = i & 511;
    W2T[i] = f2bf(W2[(k << 9) | n]);
  }
}

// ---------- row magnitudes: mags[b*T+t] = ||x[b,t,:]||_2  (4 rows/block)
__global__ void k_mags(const float* __restrict__ x, float* __restrict__ mags){
  int wid = threadIdx.x >> 6, lane = threadIdx.x & 63;
  int row = blockIdx.x * 4 + wid;
  const float* xr = x + row * ND;
  float s = 0.f;
#pragma unroll
  for (int i = 0; i < 8; i++){ float v = xr[lane + 64*i]; s += v*v; }
#pragma unroll
  for (int off = 32; off; off >>= 1) s += __shfl_xor(s, off, 64);
  if (lane == 0) mags[row] = sqrtf(s);
}

// ---------- exact top-k selection by ranking; 4 threads per t, 64 t per block
__global__ void k_select(const float* __restrict__ mags, int* __restrict__ sel){
  __shared__ float sm[NT];
  int b = blockIdx.x;
  int tid = threadIdx.x;
  for (int i = tid; i < NT; i += 256) sm[i] = mags[b * NT + i];
  __syncthreads();
  int tl = tid >> 2, tq = tid & 3;
  int t = blockIdx.y * 64 + tl;
  float m = sm[t];
  int cnt = 0;
  int s0 = tq * 256;
  for (int s = s0; s < s0 + 256; s++){
    float v = sm[s];
    cnt += (v > m) || (v == m && s < t);
  }
  cnt += __shfl_xor(cnt, 1, 64);
  cnt += __shfl_xor(cnt, 2, 64);
  if (tq == 0) sel[b * NT + t] = (cnt < KSEL) ? 1 : 0;
}

// ---------- MFMA bf16 GEMM: Wh = bf16(x) @ Wcat ; epilogue fuses:
//   es/ed (edge dot products, f32), WhT[(b*512+n)][t] transposed bf16 write
__launch_bounds__(256)
__global__ void k_gemm_wh(const float* __restrict__ x, const u16* __restrict__ Bt,
                          const float* __restrict__ a_src, const float* __restrict__ a_dst,
                          u16* __restrict__ WhT, float* __restrict__ es, float* __restrict__ ed){
  __shared__ u16 smem[128 * TSTR];   // 34816 B; aliases As/Bs during K-loop
  u16* As = smem;                    // 128*40
  u16* Bs = smem + 5120;             // 128*40
  int m0 = blockIdx.x * 128, n0 = blockIdx.y * 128;
  int tid = threadIdx.x;
  int wv = tid >> 6, lane = tid & 63;
  int wr = wv & 1, wc = wv >> 1;
  int quad = lane >> 4, lr = lane & 15;
  f32x4 acc[4][4] = {};
  for (int kt = 0; kt < 512; kt += 32){
    __syncthreads();
#pragma unroll
    for (int i = 0; i < 2; i++){
      int e = tid * 8 + i * 2048;
      int r = e >> 5, c = e & 31;
      const float* xa = &x[(m0 + r) * 512 + kt + c];
      f32x4 u0 = *(const f32x4*)xa;
      f32x4 u1 = *(const f32x4*)(xa + 4);
      u16 pk[8];
#pragma unroll
      for (int q = 0; q < 4; q++){ pk[q] = f2bf(u0[q]); pk[4+q] = f2bf(u1[q]); }
      *(bf16x8*)&As[r*40 + c] = *(const bf16x8*)pk;
      *(bf16x8*)&Bs[r*40 + c] = *(const bf16x8*)&Bt[(n0 + r) * 512 + kt + c];
    }
    __syncthreads();
    bf16x8 af[4], bfr[4];
#pragma unroll
    for (int i = 0; i < 4; i++){
      af[i]  = *(const bf16x8*)&As[(wr*64 + i*16 + lr)*40 + quad*8];
      bfr[i] = *(const bf16x8*)&Bs[(wc*64 + i*16 + lr)*40 + quad*8];
    }
#pragma unroll
    for (int mi = 0; mi < 4; mi++)
#pragma unroll
      for (int ni = 0; ni < 4; ni++)
        acc[mi][ni] = __builtin_amdgcn_mfma_f32_16x16x32_bf16(af[mi], bfr[ni], acc[mi][ni], 0, 0, 0);
  }
  // ---- epilogue 1: edge dot products (wave owns head h, rows wr*64..+64)
  int h = (n0 >> 6) + wc;
  float asv[4], adv[4];
#pragma unroll
  for (int ni = 0; ni < 4; ni++){
    int colg = n0 + wc*64 + ni*16 + lr;
    asv[ni] = a_src[colg & 511];
    adv[ni] = a_dst[colg & 511];
  }
#pragma unroll
  for (int mi = 0; mi < 4; mi++)
#pragma unroll
    for (int r = 0; r < 4; r++){
      float pes = 0.f, ped = 0.f;
#pragma unroll
      for (int ni = 0; ni < 4; ni++){
        pes += acc[mi][ni][r] * asv[ni];
        ped += acc[mi][ni][r] * adv[ni];
      }
#pragma unroll
      for (int mofs = 1; mofs < 16; mofs <<= 1){
        pes += __shfl_xor(pes, mofs, 64);
        ped += __shfl_xor(ped, mofs, 64);
      }
      if (lr == 0){
        int rowg = m0 + wr*64 + mi*16 + quad*4 + r;
        int bb_ = rowg >> 10, tt = rowg & 1023;
        es[(bb_ * 8 + h) * NT + tt] = pes;
        ed[(bb_ * 8 + h) * NT + tt] = ped;
      }
    }
  // ---- epilogue 2: bf16 transpose via LDS -> WhT
  __syncthreads();
  u16* Tr = smem;   // [c][t], stride TSTR
#pragma unroll
  for (int mi = 0; mi < 4; mi++)
#pragma unroll
    for (int ni = 0; ni < 4; ni++){
      int cl = wc*64 + ni*16 + lr;
      int tl = wr*64 + mi*16 + quad*4;
#pragma unroll
      for (int r = 0; r < 4; r++) Tr[cl*TSTR + tl + r] = f2bf(acc[mi][ni][r]);
    }
  __syncthreads();
  int c = tid >> 1, hf = tid & 1;
  int b2_ = m0 >> 10;
  u16* dst = &WhT[(b2_ * 512 + n0 + c) * NT + (m0 & 1023) + hf*64];
  const u16* srcp = &Tr[c*TSTR + hf*64];
#pragma unroll
  for (int k8 = 0; k8 < 8; k8++)
    *(bf16x8*)(dst + k8*8) = *(const bf16x8*)(srcp + k8*8);
}

// ---------- banded masked attention via MFMA + elu + signed-sqrt -> t2b (bf16)
//            + fused column sum-of-squares (atomicAdd into cn)
__launch_bounds__(256)
__global__ void k_attn(const u16* __restrict__ WhT, const float* __restrict__ es,
                       const float* __restrict__ ed, const int* __restrict__ sel,
                       u16* __restrict__ t2b, float* __restrict__ cn){
  __shared__ u16 P[64 * PSTR];
  __shared__ float edw[144];
  __shared__ int   selw[144];
  __shared__ float esw[64];
  __shared__ float swv[64];
  int bh = blockIdx.x;               // b*8+h
  int b = bh >> 3;
  int t0 = blockIdx.y * 64;
  int tid = threadIdx.x;
  int wv = tid >> 6, lane = tid & 63;
  int quad = lane >> 4, lr = lane & 15;
  int s_base = t0 - 40;
  for (int i = tid; i < 144; i += 256){
    int s = s_base + i;
    bool ok = (s >= 0 && s < NT);
    edw[i]  = ok ? ed[bh * NT + s] : 0.f;
    selw[i] = ok ? sel[b * NT + s] : 0;
  }
  if (tid < 64) esw[tid] = es[bh * NT + t0 + tid];
  {
    i32x4 z = {};
    for (int i = lane; i < 304; i += 64){
      int r16 = i / 19, c16 = i - r16 * 19;
      *(i32x4*)&P[(16*wv + r16) * PSTR + c16 * 8] = z;
    }
  }
  __syncthreads();
  {
    int tl = 16*wv + (lane >> 2);
    int q = lane & 3;
    float e_t = esw[tl];
    int sel_t = selw[tl + 40];
    float part = 0.f;
    for (int j = q; j <= 80; j += 4){
      int sw = tl + j;
      int s = s_base + sw;
      float w = 0.f;
      if (s >= 0 && s < NT && (sel_t | selw[sw])){
        float v = e_t + edw[sw];
        v = v > 0.f ? v : 0.2f * v;
        v = fminf(v, 60.f);
        w = bf2f(f2bf(__expf(v)));
      }
      part += w;
      if (w != 0.f) P[tl * PSTR + sw] = f2bf(w);
    }
    part += __shfl_xor(part, 1, 64);
    part += __shfl_xor(part, 2, 64);
    if (q == 0) swv[tl] = part;
  }
  f32x4 acc[4] = {};
  const u16* vbase = WhT + (bh * 64) * NT;
#pragma unroll
  for (int ks = 0; ks < 96; ks += 32){
    bf16x8 afr = *(const bf16x8*)&P[(16*wv + lr) * PSTR + 16*wv + ks + quad*8];
    int tb = s_base + 16*wv + ks + quad*8;
    bool ok = (tb >= 0) && (tb < NT);
    bf16x8 zf = {};
#pragma unroll
    for (int jn = 0; jn < 4; jn++){
      bf16x8 bfr = ok ? *(const bf16x8*)&vbase[(16*jn + lr) * NT + tb] : zf;
      acc[jn] = __builtin_amdgcn_mfma_f32_16x16x32_bf16(afr, bfr, acc[jn], 0, 0, 0);
    }
  }
#pragma unroll
  for (int jn = 0; jn < 4; jn++){
    float ssum = 0.f;
#pragma unroll
    for (int r = 0; r < 4; r++){
      int t_loc = 16*wv + quad*4 + r;
      float sw_ = swv[t_loc];
      float hp = acc[jn][r] / (sw_ > 0.f ? sw_ : 1.f);
      hp = hp > 0.f ? hp : (__expf(hp) - 1.f);
      float o = hp >= 0.f ? sqrtf(hp) : -sqrtf(-hp);
      ssum += o * o;
      t2b[(b * NT + t0 + t_loc) * ND + (bh & 7) * 64 + 16*jn + lr] = f2bf(o);
    }
    ssum += __shfl_xor(ssum, 16, 64);
    ssum += __shfl_xor(ssum, 32, 64);
    if (quad == 0) atomicAdd(&cn[b * ND + (bh & 7) * 64 + 16*jn + lr], ssum);
  }
}

// ---------- tmp / max(||tmp||_T, eps) -> bf16 (in-place)
__global__ void k_normalize(const u16* __restrict__ t2b, const float* __restrict__ cn,
                            u16* __restrict__ tmpb){
  int idx = (blockIdx.x * 256 + threadIdx.x) * 8;
  int b = idx >> 19;
#pragma unroll
  for (int i = 0; i < 8; i++){
    int id = idx + i;
    int d = id & 511;
    float nv = sqrtf(cn[b * ND + d]);
    float v = bf2f(t2b[id]) / fmaxf(nv, 1e-12f);
    tmpb[id] = f2bf(v);
  }
}

// ---------- GEMM2: Y(f32) = tmpb @ W2 + x + b2
__launch_bounds__(256)
__global__ void k_gemm2(const u16* __restrict__ A, const u16* __restrict__ Bt,
                        const float* __restrict__ xres, const float* __restrict__ b2,
                        float* __restrict__ Y){
  __shared__ u16 As[128 * 40];
  __shared__ u16 Bs[128 * 40];
  int m0 = blockIdx.x * 128, n0 = blockIdx.y * 128;
  int tid = threadIdx.x;
  int wv = tid >> 6, lane = tid & 63;
  int wr = wv & 1, wc = wv >> 1;
  int quad = lane >> 4, lr = lane & 15;
  f32x4 acc[4][4] = {};
  for (int kt = 0; kt < 512; kt += 32){
    __syncthreads();
#pragma unroll
    for (int i = 0; i < 2; i++){
      int e = tid * 8 + i * 2048;
      int r = e >> 5, c = e & 31;
      *(bf16x8*)&As[r*40 + c] = *(const bf16x8*)&A[(m0 + r) * 512 + kt + c];
      *(bf16x8*)&Bs[r*40 + c] = *(const bf16x8*)&Bt[(n0 + r) * 512 + kt + c];
    }
    __syncthreads();
    bf16x8 af[4], bfr[4];
#pragma unroll
    for (int i = 0; i < 4; i++){
      af[i]  = *(const bf16x8*)&As[(wr*64 + i*16 + lr)*40 + quad*8];
      bfr[i] = *(const bf16x8*)&Bs[(wc*64 + i*16 + lr)*40 + quad*8];
    }
#pragma unroll
    for (int mi = 0; mi < 4; mi++)
#pragma unroll
      for (int ni = 0; ni < 4; ni++)
        acc[mi][ni] = __builtin_amdgcn_mfma_f32_16x16x32_bf16(af[mi], bfr[ni], acc[mi][ni], 0, 0, 0);
  }
#pragma unroll
  for (int mi = 0; mi < 4; mi++)
#pragma unroll
    for (int ni = 0; ni < 4; ni++){
      int rg = m0 + wr*64 + mi*16 + quad*4;
      int cg = n0 + wc*64 + ni*16 + lr;
#pragma unroll
      for (int r = 0; r < 4; r++){
        int idx = (rg + r) * 512 + cg;
        Y[idx] = acc[mi][ni][r] + xres[idx] + b2[cg];
      }
    }
}

// ---------- fused LN stats + apply + transpose to out[b, d, t] (f32)
__global__ void k_outln(const float* __restrict__ Y, const float* __restrict__ g,
                        const float* __restrict__ bb, float* __restrict__ out){
  __shared__ float mus[64], rss[64];
  __shared__ float tile[64 * 65];
  int t0 = blockIdx.x * 64, b = blockIdx.y;
  int tid = threadIdx.x;
  int wv = tid >> 6, lane = tid & 63;
  // pass 1: row stats (wave wv owns rows wv*16..+16)
  for (int i = 0; i < 16; i++){
    int row = b * NT + t0 + wv*16 + i;
    const float* yr = Y + row * ND;
    float s = 0.f, q = 0.f;
#pragma unroll
    for (int k = 0; k < 8; k++){ float v = yr[lane + 64*k]; s += v; q += v*v; }
#pragma unroll
    for (int off = 32; off; off >>= 1){ s += __shfl_xor(s, off, 64); q += __shfl_xor(q, off, 64); }
    if (lane == 0){
      float m = s * (1.f/512.f);
      float var = q * (1.f/512.f) - m * m;
      mus[wv*16 + i] = m;
      rss[wv*16 + i] = 1.f / sqrtf(var + 1e-5f);
    }
  }
  __syncthreads();
  // pass 2: apply + transpose, 64-column chunks
  int j = tid & 63, i0 = tid >> 6;
  for (int c0 = 0; c0 < 512; c0 += 64){
#pragma unroll
    for (int k = 0; k < 16; k++){
      int i = i0 + k * 4;
      float v = (Y[(b * NT + t0 + i) * ND + c0 + j] - mus[i]) * rss[i] * g[c0 + j] + bb[c0 + j];
      tile[i * 65 + j] = v;
    }
    __syncthreads();
#pragma unroll
    for (int k = 0; k < 16; k++){
      int jj = i0 + k * 4;   // d-local
      out[(b * ND + c0 + jj) * NT + t0 + j] = tile[j * 65 + jj];
    }
    __syncthreads();
  }
}

extern "C" void kernel_launch(void* const* d_in, const int* in_sizes, int n_in,
                              void* d_out, int out_size, void* d_ws, size_t ws_size,
                              hipStream_t stream) {
  (void)in_sizes; (void)n_in; (void)out_size; (void)ws_size;
  const float* x     = (const float*)d_in[0];
  const float* W     = (const float*)d_in[1];
  const float* a_src = (const float*)d_in[2];
  const float* a_dst = (const float*)d_in[3];
  const float* W2    = (const float*)d_in[4];
  const float* b2    = (const float*)d_in[5];
  const float* ln_g  = (const float*)d_in[6];
  const float* ln_b  = (const float*)d_in[7];
  char* ws = (char*)d_ws;
  int*   sel   = (int*)  (ws + 256);
  float* mags  = (float*)(ws + 33024);
  u16*   WcatT = (u16*)  (ws + 65792);
  u16*   W2T   = (u16*)  (ws + 590080);
  float* es    = (float*)(ws + 1124608);
  float* ed    = (float*)(ws + 1386752);
  float* cn    = (float*)(ws + 1648896);
  u16*   WhT   = (u16*)  (ws + 2097152);   // 8 MB; dead after k_attn
  u16*   t2b   = (u16*)  (ws + 18874368);  // 8 MB; normalize in-place
  u16*   tmpb  = t2b;
  float* Y     = (float*)(ws + 2097152);   // 16 MB; overlays WhT after dead
  float* out   = (float*)d_out;

  k_mags     <<<2048, 256, 0, stream>>>(x, mags);
  k_select   <<<dim3(NB, 16), 256, 0, stream>>>(mags, sel);
  k_convert_w<<<2048, 256, 0, stream>>>(W, W2, WcatT, W2T);
  hipMemsetAsync(cn, 0, NB * ND * sizeof(float), stream);
  k_gemm_wh  <<<dim3(64, 4), 256, 0, stream>>>(x, WcatT, a_src, a_dst, WhT, es, ed);
  k_attn     <<<dim3(64, 16), 256, 0, stream>>>(WhT, es, ed, sel, t2b, cn);
  k_normalize<<<2048, 256, 0, stream>>>(t2b, cn, tmpb);
  k_gemm2    <<<dim3(64, 4), 256, 0, stream>>>(tmpb, W2T, x, b2, Y);
  k_outln    <<<dim3(16, NB), 256, 0, stream>>>(Y, ln_g, ln_b, out);
}

// Round 7
// 169.988 us; speedup vs baseline: 2.0951x; 1.0562x over previous
//
#include <hip/hip_runtime.h>
#include <hip/hip_bf16.h>

typedef unsigned short u16;
typedef short bf16x8 __attribute__((ext_vector_type(8)));
typedef float f32x4 __attribute__((ext_vector_type(4)));
typedef int   i32x4 __attribute__((ext_vector_type(4)));

#define NB 8
#define NT 1024
#define ND 512
#define KSEL 307
#define PSTR 152   // attn P LDS row stride (elems)
#define TSTR 136   // gemm_wh transpose LDS row stride (elems)

__device__ __forceinline__ float bf2f(u16 u){
  union { unsigned int i; float f; } c; c.i = ((unsigned int)u) << 16; return c.f;
}
__device__ __forceinline__ u16 f2bf(float f){
  __hip_bfloat16 h = __float2bfloat16(f);
  u16 u; __builtin_memcpy(&u, &h, 2); return u;
}

// ---------- WcatT[c][d] = W[h=c>>6][d][f=c&63];  W2T[n][k] = W2[k][n]  (bf16)
__global__ void k_convert_w(const float* __restrict__ W, const float* __restrict__ W2,
                            u16* __restrict__ WcatT, u16* __restrict__ W2T){
  int idx = blockIdx.x * 256 + threadIdx.x;          // 0 .. 524287
  if (idx < 262144){
    int c = idx >> 9, d = idx & 511;
    int src = ((c >> 6) << 15) | (d << 6) | (c & 63);
    WcatT[idx] = f2bf(W[src]);
  } else {
    int i = idx - 262144;
    int n = i >> 9, k = i & 511;
    W2T[i] = f2bf(W2[(k << 9) | n]);
  }
}

// ---------- exact top-k selection by ranking; 4 threads per t, 64 t per block
__global__ void k_select(const float* __restrict__ mags, int* __restrict__ sel){
  __shared__ float sm[NT];
  int b = blockIdx.x;
  int tid = threadIdx.x;
  for (int i = tid; i < NT; i += 256) sm[i] = mags[b * NT + i];
  __syncthreads();
  int tl = tid >> 2, tq = tid & 3;
  int t = blockIdx.y * 64 + tl;
  float m = sm[t];
  int cnt = 0;
  int s0 = tq * 256;
  for (int s = s0; s < s0 + 256; s++){
    float v = sm[s];
    cnt += (v > m) || (v == m && s < t);
  }
  cnt += __shfl_xor(cnt, 1, 64);
  cnt += __shfl_xor(cnt, 2, 64);
  if (tq == 0) sel[b * NT + t] = (cnt < KSEL) ? 1 : 0;
}

// ---------- MFMA bf16 GEMM: Wh = bf16(x) @ Wcat ; epilogue fuses:
//   row mags (by==0 blocks), es/ed edge dots, transposed bf16 WhT write
__launch_bounds__(256)
__global__ void k_gemm_wh(const float* __restrict__ x, const u16* __restrict__ Bt,
                          const float* __restrict__ a_src, const float* __restrict__ a_dst,
                          u16* __restrict__ WhT, float* __restrict__ es, float* __restrict__ ed,
                          float* __restrict__ mags){
  __shared__ u16 smem[128 * TSTR];   // 34816 B; aliases As/Bs during K-loop
  u16* As = smem;                    // 128*40
  u16* Bs = smem + 5120;             // 128*40
  int m0 = blockIdx.x * 128, n0 = blockIdx.y * 128;
  int tid = threadIdx.x;
  int wv = tid >> 6, lane = tid & 63;
  int wr = wv & 1, wc = wv >> 1;
  int quad = lane >> 4, lr = lane & 15;
  f32x4 acc[4][4] = {};
  float sq[2] = {0.f, 0.f};
  for (int kt = 0; kt < 512; kt += 32){
    __syncthreads();
#pragma unroll
    for (int i = 0; i < 2; i++){
      int e = tid * 8 + i * 2048;
      int r = e >> 5, c = e & 31;
      const float* xa = &x[(m0 + r) * 512 + kt + c];
      f32x4 u0 = *(const f32x4*)xa;
      f32x4 u1 = *(const f32x4*)(xa + 4);
      u16 pk[8];
#pragma unroll
      for (int q = 0; q < 4; q++){
        sq[i] += u0[q]*u0[q] + u1[q]*u1[q];
        pk[q] = f2bf(u0[q]); pk[4+q] = f2bf(u1[q]);
      }
      *(bf16x8*)&As[r*40 + c] = *(const bf16x8*)pk;
      *(bf16x8*)&Bs[r*40 + c] = *(const bf16x8*)&Bt[(n0 + r) * 512 + kt + c];
    }
    __syncthreads();
    bf16x8 af[4], bfr[4];
#pragma unroll
    for (int i = 0; i < 4; i++){
      af[i]  = *(const bf16x8*)&As[(wr*64 + i*16 + lr)*40 + quad*8];
      bfr[i] = *(const bf16x8*)&Bs[(wc*64 + i*16 + lr)*40 + quad*8];
    }
#pragma unroll
    for (int mi = 0; mi < 4; mi++)
#pragma unroll
      for (int ni = 0; ni < 4; ni++)
        acc[mi][ni] = __builtin_amdgcn_mfma_f32_16x16x32_bf16(af[mi], bfr[ni], acc[mi][ni], 0, 0, 0);
  }
  // ---- epilogue 0: row L2 norms (4 lanes per row, rows tid/4 and 64+tid/4)
  if (blockIdx.y == 0){
#pragma unroll
    for (int i = 0; i < 2; i++){
      float s = sq[i];
      s += __shfl_xor(s, 1, 64);
      s += __shfl_xor(s, 2, 64);
      if ((tid & 3) == 0) mags[m0 + i*64 + (tid >> 2)] = sqrtf(s);
    }
  }
  // ---- epilogue 1: edge dot products (wave owns head h, rows wr*64..+64)
  int h = (n0 >> 6) + wc;
  float asv[4], adv[4];
#pragma unroll
  for (int ni = 0; ni < 4; ni++){
    int colg = n0 + wc*64 + ni*16 + lr;
    asv[ni] = a_src[colg & 511];
    adv[ni] = a_dst[colg & 511];
  }
#pragma unroll
  for (int mi = 0; mi < 4; mi++)
#pragma unroll
    for (int r = 0; r < 4; r++){
      float pes = 0.f, ped = 0.f;
#pragma unroll
      for (int ni = 0; ni < 4; ni++){
        pes += acc[mi][ni][r] * asv[ni];
        ped += acc[mi][ni][r] * adv[ni];
      }
#pragma unroll
      for (int mofs = 1; mofs < 16; mofs <<= 1){
        pes += __shfl_xor(pes, mofs, 64);
        ped += __shfl_xor(ped, mofs, 64);
      }
      if (lr == 0){
        int rowg = m0 + wr*64 + mi*16 + quad*4 + r;
        int bb_ = rowg >> 10, tt = rowg & 1023;
        es[(bb_ * 8 + h) * NT + tt] = pes;
        ed[(bb_ * 8 + h) * NT + tt] = ped;
      }
    }
  // ---- epilogue 2: bf16 transpose via LDS -> WhT
  __syncthreads();
  u16* Tr = smem;   // [c][t], stride TSTR
#pragma unroll
  for (int mi = 0; mi < 4; mi++)
#pragma unroll
    for (int ni = 0; ni < 4; ni++){
      int cl = wc*64 + ni*16 + lr;
      int tl = wr*64 + mi*16 + quad*4;
#pragma unroll
      for (int r = 0; r < 4; r++) Tr[cl*TSTR + tl + r] = f2bf(acc[mi][ni][r]);
    }
  __syncthreads();
  int c = tid >> 1, hf = tid & 1;
  int b2_ = m0 >> 10;
  u16* dst = &WhT[(b2_ * 512 + n0 + c) * NT + (m0 & 1023) + hf*64];
  const u16* srcp = &Tr[c*TSTR + hf*64];
#pragma unroll
  for (int k8 = 0; k8 < 8; k8++)
    *(bf16x8*)(dst + k8*8) = *(const bf16x8*)(srcp + k8*8);
}

// ---------- banded masked attention via MFMA + elu + signed-sqrt -> t2b (bf16)
//            + fused column sum-of-squares (atomicAdd into cn)
__launch_bounds__(256)
__global__ void k_attn(const u16* __restrict__ WhT, const float* __restrict__ es,
                       const float* __restrict__ ed, const int* __restrict__ sel,
                       u16* __restrict__ t2b, float* __restrict__ cn){
  __shared__ u16 P[64 * PSTR];
  __shared__ float edw[144];
  __shared__ int   selw[144];
  __shared__ float esw[64];
  __shared__ float swv[64];
  int bh = blockIdx.x;               // b*8+h
  int b = bh >> 3;
  int t0 = blockIdx.y * 64;
  int tid = threadIdx.x;
  int wv = tid >> 6, lane = tid & 63;
  int quad = lane >> 4, lr = lane & 15;
  int s_base = t0 - 40;
  for (int i = tid; i < 144; i += 256){
    int s = s_base + i;
    bool ok = (s >= 0 && s < NT);
    edw[i]  = ok ? ed[bh * NT + s] : 0.f;
    selw[i] = ok ? sel[b * NT + s] : 0;
  }
  if (tid < 64) esw[tid] = es[bh * NT + t0 + tid];
  {
    i32x4 z = {};
    for (int i = lane; i < 304; i += 64){
      int r16 = i / 19, c16 = i - r16 * 19;
      *(i32x4*)&P[(16*wv + r16) * PSTR + c16 * 8] = z;
    }
  }
  __syncthreads();
  {
    int tl = 16*wv + (lane >> 2);
    int q = lane & 3;
    float e_t = esw[tl];
    int sel_t = selw[tl + 40];
    float part = 0.f;
    for (int j = q; j <= 80; j += 4){
      int sw = tl + j;
      int s = s_base + sw;
      float w = 0.f;
      if (s >= 0 && s < NT && (sel_t | selw[sw])){
        float v = e_t + edw[sw];
        v = v > 0.f ? v : 0.2f * v;
        v = fminf(v, 60.f);
        w = bf2f(f2bf(__expf(v)));
      }
      part += w;
      if (w != 0.f) P[tl * PSTR + sw] = f2bf(w);
    }
    part += __shfl_xor(part, 1, 64);
    part += __shfl_xor(part, 2, 64);
    if (q == 0) swv[tl] = part;
  }
  f32x4 acc[4] = {};
  const u16* vbase = WhT + (bh * 64) * NT;
#pragma unroll
  for (int ks = 0; ks < 96; ks += 32){
    bf16x8 afr = *(const bf16x8*)&P[(16*wv + lr) * PSTR + 16*wv + ks + quad*8];
    int tb = s_base + 16*wv + ks + quad*8;
    bool ok = (tb >= 0) && (tb < NT);
    bf16x8 zf = {};
#pragma unroll
    for (int jn = 0; jn < 4; jn++){
      bf16x8 bfr = ok ? *(const bf16x8*)&vbase[(16*jn + lr) * NT + tb] : zf;
      acc[jn] = __builtin_amdgcn_mfma_f32_16x16x32_bf16(afr, bfr, acc[jn], 0, 0, 0);
    }
  }
#pragma unroll
  for (int jn = 0; jn < 4; jn++){
    float ssum = 0.f;
#pragma unroll
    for (int r = 0; r < 4; r++){
      int t_loc = 16*wv + quad*4 + r;
      float sw_ = swv[t_loc];
      float hp = acc[jn][r] / (sw_ > 0.f ? sw_ : 1.f);
      hp = hp > 0.f ? hp : (__expf(hp) - 1.f);
      float o = hp >= 0.f ? sqrtf(hp) : -sqrtf(-hp);
      ssum += o * o;
      t2b[(b * NT + t0 + t_loc) * ND + (bh & 7) * 64 + 16*jn + lr] = f2bf(o);
    }
    ssum += __shfl_xor(ssum, 16, 64);
    ssum += __shfl_xor(ssum, 32, 64);
    if (quad == 0) atomicAdd(&cn[b * ND + (bh & 7) * 64 + 16*jn + lr], ssum);
  }
}

// ---------- GEMM2: Y(f32) = (t2b * scl) @ W2 + x + b2 ; fused LN partial stats
__launch_bounds__(256)
__global__ void k_gemm2(const u16* __restrict__ A, const u16* __restrict__ Bt,
                        const float* __restrict__ xres, const float* __restrict__ b2,
                        const float* __restrict__ cn, float* __restrict__ Y,
                        float* __restrict__ rsum, float* __restrict__ rqsum){
  __shared__ u16 As[128 * 40];
  __shared__ u16 Bs[128 * 40];
  __shared__ float scl[512];
  int m0 = blockIdx.x * 128, n0 = blockIdx.y * 128;
  int tid = threadIdx.x;
  int wv = tid >> 6, lane = tid & 63;
  int wr = wv & 1, wc = wv >> 1;
  int quad = lane >> 4, lr = lane & 15;
  // normalize scale for this block's batch (rows m0..m0+127 share b)
  int bb0 = (m0 >> 10) << 9;          // b*512
  for (int i = tid; i < 512; i += 256){
    float nv = sqrtf(cn[bb0 + i]);
    scl[i] = 1.f / fmaxf(nv, 1e-12f);
  }
  f32x4 acc[4][4] = {};
  for (int kt = 0; kt < 512; kt += 32){
    __syncthreads();
#pragma unroll
    for (int i = 0; i < 2; i++){
      int e = tid * 8 + i * 2048;
      int r = e >> 5, c = e & 31;
      bf16x8 raw = *(const bf16x8*)&A[(m0 + r) * 512 + kt + c];
      u16 pk[8];
#pragma unroll
      for (int q = 0; q < 8; q++)
        pk[q] = f2bf(bf2f((u16)raw[q]) * scl[kt + c + q]);
      *(bf16x8*)&As[r*40 + c] = *(const bf16x8*)pk;
      *(bf16x8*)&Bs[r*40 + c] = *(const bf16x8*)&Bt[(n0 + r) * 512 + kt + c];
    }
    __syncthreads();
    bf16x8 af[4], bfr[4];
#pragma unroll
    for (int i = 0; i < 4; i++){
      af[i]  = *(const bf16x8*)&As[(wr*64 + i*16 + lr)*40 + quad*8];
      bfr[i] = *(const bf16x8*)&Bs[(wc*64 + i*16 + lr)*40 + quad*8];
    }
#pragma unroll
    for (int mi = 0; mi < 4; mi++)
#pragma unroll
      for (int ni = 0; ni < 4; ni++)
        acc[mi][ni] = __builtin_amdgcn_mfma_f32_16x16x32_bf16(af[mi], bfr[ni], acc[mi][ni], 0, 0, 0);
  }
  float b2v[4];
#pragma unroll
  for (int ni = 0; ni < 4; ni++) b2v[ni] = b2[n0 + wc*64 + ni*16 + lr];
#pragma unroll
  for (int mi = 0; mi < 4; mi++){
    int rgb = m0 + wr*64 + mi*16 + quad*4;
#pragma unroll
    for (int r = 0; r < 4; r++){
      int row = rgb + r;
      float rs = 0.f, rq = 0.f;
#pragma unroll
      for (int ni = 0; ni < 4; ni++){
        int cg = n0 + wc*64 + ni*16 + lr;
        int idx = row * 512 + cg;
        float yv = acc[mi][ni][r] + xres[idx] + b2v[ni];
        Y[idx] = yv;
        rs += yv; rq += yv * yv;
      }
#pragma unroll
      for (int m2 = 1; m2 < 16; m2 <<= 1){
        rs += __shfl_xor(rs, m2, 64);
        rq += __shfl_xor(rq, m2, 64);
      }
      if (lr == 0){
        atomicAdd(&rsum[row], rs);
        atomicAdd(&rqsum[row], rq);
      }
    }
  }
}

// ---------- LN apply (stats precomputed) + transpose to out[b, d, t] (f32)
__global__ void k_outln(const float* __restrict__ Y, const float* __restrict__ rsum,
                        const float* __restrict__ rqsum, const float* __restrict__ g,
                        const float* __restrict__ bb, float* __restrict__ out){
  __shared__ float mus[64], rss[64];
  __shared__ float tile[64 * 65];
  int t0 = blockIdx.x * 64, b = blockIdx.y;
  int tid = threadIdx.x;
  if (tid < 64){
    int row = b * NT + t0 + tid;
    float m = rsum[row] * (1.f/512.f);
    float var = rqsum[row] * (1.f/512.f) - m * m;
    mus[tid] = m;
    rss[tid] = 1.f / sqrtf(var + 1e-5f);
  }
  __syncthreads();
  int j = tid & 63, i0 = tid >> 6;
  for (int c0 = 0; c0 < 512; c0 += 64){
#pragma unroll
    for (int k = 0; k < 16; k++){
      int i = i0 + k * 4;
      float v = (Y[(b * NT + t0 + i) * ND + c0 + j] - mus[i]) * rss[i] * g[c0 + j] + bb[c0 + j];
      tile[i * 65 + j] = v;
    }
    __syncthreads();
#pragma unroll
    for (int k = 0; k < 16; k++){
      int jj = i0 + k * 4;   // d-local
      out[(b * ND + c0 + jj) * NT + t0 + j] = tile[j * 65 + jj];
    }
    __syncthreads();
  }
}

extern "C" void kernel_launch(void* const* d_in, const int* in_sizes, int n_in,
                              void* d_out, int out_size, void* d_ws, size_t ws_size,
                              hipStream_t stream) {
  (void)in_sizes; (void)n_in; (void)out_size; (void)ws_size;
  const float* x     = (const float*)d_in[0];
  const float* W     = (const float*)d_in[1];
  const float* a_src = (const float*)d_in[2];
  const float* a_dst = (const float*)d_in[3];
  const float* W2    = (const float*)d_in[4];
  const float* b2    = (const float*)d_in[5];
  const float* ln_g  = (const float*)d_in[6];
  const float* ln_b  = (const float*)d_in[7];
  char* ws = (char*)d_ws;
  int*   sel   = (int*)  (ws + 256);
  float* mags  = (float*)(ws + 33024);
  u16*   WcatT = (u16*)  (ws + 65792);
  u16*   W2T   = (u16*)  (ws + 590080);
  float* es    = (float*)(ws + 1124608);
  float* ed    = (float*)(ws + 1386752);
  float* cn    = (float*)(ws + 1648896);   // 16 KB
  float* rsum  = (float*)(ws + 1665280);   // 32 KB
  float* rqsum = (float*)(ws + 1698048);   // 32 KB
  u16*   WhT   = (u16*)  (ws + 2097152);   // 8 MB; dead after k_attn
  u16*   t2b   = (u16*)  (ws + 18874368);  // 8 MB
  float* Y     = (float*)(ws + 2097152);   // 16 MB; overlays WhT after dead
  float* out   = (float*)d_out;

  k_convert_w<<<2048, 256, 0, stream>>>(W, W2, WcatT, W2T);
  hipMemsetAsync(cn, 0, 81920, stream);    // cn + rsum + rqsum
  k_gemm_wh  <<<dim3(64, 4), 256, 0, stream>>>(x, WcatT, a_src, a_dst, WhT, es, ed, mags);
  k_select   <<<dim3(NB, 16), 256, 0, stream>>>(mags, sel);
  k_attn     <<<dim3(64, 16), 256, 0, stream>>>(WhT, es, ed, sel, t2b, cn);
  k_gemm2    <<<dim3(64, 4), 256, 0, stream>>>(t2b, W2T, x, b2, cn, Y, rsum, rqsum);
  k_outln    <<<dim3(16, NB), 256, 0, stream>>>(Y, rsum, rqsum, ln_g, ln_b, out);
}

// Round 8
// 162.221 us; speedup vs baseline: 2.1954x; 1.0479x over previous
//
#include <hip/hip_runtime.h>
#include <hip/hip_bf16.h>

typedef unsigned short u16;
typedef short bf16x8 __attribute__((ext_vector_type(8)));
typedef float f32x4 __attribute__((ext_vector_type(4)));
typedef int   i32x4 __attribute__((ext_vector_type(4)));

#define NB 8
#define NT 1024
#define ND 512
#define KSEL 307
#define PSTR 152   // attn P LDS row stride (elems)
#define TSTR 136   // gemm_wh transpose LDS row stride (elems)

__device__ __forceinline__ float bf2f(u16 u){
  union { unsigned int i; float f; } c; c.i = ((unsigned int)u) << 16; return c.f;
}
__device__ __forceinline__ u16 f2bf(float f){
  __hip_bfloat16 h = __float2bfloat16(f);
  u16 u; __builtin_memcpy(&u, &h, 2); return u;
}

// ---------- WcatT[c][d] = W[h=c>>6][d][f=c&63];  W2T[n][k] = W2[k][n]  (bf16)
__global__ void k_convert_w(const float* __restrict__ W, const float* __restrict__ W2,
                            u16* __restrict__ WcatT, u16* __restrict__ W2T){
  int idx = blockIdx.x * 256 + threadIdx.x;          // 0 .. 524287
  if (idx < 262144){
    int c = idx >> 9, d = idx & 511;
    int src = ((c >> 6) << 15) | (d << 6) | (c & 63);
    WcatT[idx] = f2bf(W[src]);
  } else {
    int i = idx - 262144;
    int n = i >> 9, k = i & 511;
    W2T[i] = f2bf(W2[(k << 9) | n]);
  }
}

// ---------- exact top-k selection by ranking; 4 threads per t, 64 t per block
__global__ void k_select(const float* __restrict__ mags, int* __restrict__ sel){
  __shared__ float sm[NT];
  int b = blockIdx.x;
  int tid = threadIdx.x;
  for (int i = tid; i < NT; i += 256) sm[i] = mags[b * NT + i];
  __syncthreads();
  int tl = tid >> 2, tq = tid & 3;
  int t = blockIdx.y * 64 + tl;
  float m = sm[t];
  int cnt = 0;
  int s0 = tq * 256;
  for (int s = s0; s < s0 + 256; s++){
    float v = sm[s];
    cnt += (v > m) || (v == m && s < t);
  }
  cnt += __shfl_xor(cnt, 1, 64);
  cnt += __shfl_xor(cnt, 2, 64);
  if (tq == 0) sel[b * NT + t] = (cnt < KSEL) ? 1 : 0;
}

// ---------- MFMA bf16 GEMM: Wh = bf16(x) @ Wcat ; tile 128(t) x 64(f = one head)
//   epilogue fuses: row mags (by==0), es/ed edge dots, transposed bf16 WhT write
__launch_bounds__(256, 3)
__global__ void k_gemm_wh(const float* __restrict__ x, const u16* __restrict__ Bt,
                          const float* __restrict__ a_src, const float* __restrict__ a_dst,
                          u16* __restrict__ WhT, float* __restrict__ es, float* __restrict__ ed,
                          float* __restrict__ mags){
  __shared__ u16 smem[8704];         // 17408 B; As(5120)+Bs(2560) alias Tr(64*TSTR)
  u16* As = smem;                    // 128 x 40
  u16* Bs = smem + 5120;             // 64 x 40
  int m0 = blockIdx.x * 128;         // t-block
  int h  = blockIdx.y;               // head (n0 = h*64)
  int tid = threadIdx.x;
  int wv = tid >> 6, lane = tid & 63;
  int quad = lane >> 4, lr = lane & 15;
  f32x4 acc[2][4] = {};
  float sq[2] = {0.f, 0.f};
  for (int kt = 0; kt < 512; kt += 32){
    __syncthreads();
#pragma unroll
    for (int i = 0; i < 2; i++){
      int e = tid * 8 + i * 2048;
      int r = e >> 5, c = e & 31;
      const float* xa = &x[(m0 + r) * 512 + kt + c];
      f32x4 u0 = *(const f32x4*)xa;
      f32x4 u1 = *(const f32x4*)(xa + 4);
      u16 pk[8];
#pragma unroll
      for (int q = 0; q < 4; q++){
        sq[i] += u0[q]*u0[q] + u1[q]*u1[q];
        pk[q] = f2bf(u0[q]); pk[4+q] = f2bf(u1[q]);
      }
      *(bf16x8*)&As[r*40 + c] = *(const bf16x8*)pk;
    }
    {
      int e = tid * 8;               // 0..2047 exactly covers 64x32
      int r = e >> 5, c = e & 31;
      *(bf16x8*)&Bs[r*40 + c] = *(const bf16x8*)&Bt[(h * 64 + r) * 512 + kt + c];
    }
    __syncthreads();
    bf16x8 af[2], bfr[4];
#pragma unroll
    for (int i = 0; i < 2; i++) af[i] = *(const bf16x8*)&As[(wv*32 + i*16 + lr)*40 + quad*8];
#pragma unroll
    for (int i = 0; i < 4; i++) bfr[i] = *(const bf16x8*)&Bs[(i*16 + lr)*40 + quad*8];
#pragma unroll
    for (int mi = 0; mi < 2; mi++)
#pragma unroll
      for (int ni = 0; ni < 4; ni++)
        acc[mi][ni] = __builtin_amdgcn_mfma_f32_16x16x32_bf16(af[mi], bfr[ni], acc[mi][ni], 0, 0, 0);
  }
  // ---- epilogue 0: row L2 norms (4 lanes per row)
  if (blockIdx.y == 0){
#pragma unroll
    for (int i = 0; i < 2; i++){
      float s = sq[i];
      s += __shfl_xor(s, 1, 64);
      s += __shfl_xor(s, 2, 64);
      if ((tid & 3) == 0) mags[m0 + i*64 + (tid >> 2)] = sqrtf(s);
    }
  }
  // ---- epilogue 1: edge dot products (wave owns rows wv*32..+32, full head width)
  float asv[4], adv[4];
#pragma unroll
  for (int ni = 0; ni < 4; ni++){
    asv[ni] = a_src[h*64 + ni*16 + lr];
    adv[ni] = a_dst[h*64 + ni*16 + lr];
  }
#pragma unroll
  for (int mi = 0; mi < 2; mi++)
#pragma unroll
    for (int r = 0; r < 4; r++){
      float pes = 0.f, ped = 0.f;
#pragma unroll
      for (int ni = 0; ni < 4; ni++){
        pes += acc[mi][ni][r] * asv[ni];
        ped += acc[mi][ni][r] * adv[ni];
      }
#pragma unroll
      for (int mofs = 1; mofs < 16; mofs <<= 1){
        pes += __shfl_xor(pes, mofs, 64);
        ped += __shfl_xor(ped, mofs, 64);
      }
      if (lr == 0){
        int rowg = m0 + wv*32 + mi*16 + quad*4 + r;
        int bb_ = rowg >> 10, tt = rowg & 1023;
        es[(bb_ * 8 + h) * NT + tt] = pes;
        ed[(bb_ * 8 + h) * NT + tt] = ped;
      }
    }
  // ---- epilogue 2: bf16 transpose via LDS -> WhT[(b*512 + h*64 + f)][t]
  __syncthreads();
  u16* Tr = smem;   // [f][t], stride TSTR
#pragma unroll
  for (int mi = 0; mi < 2; mi++)
#pragma unroll
    for (int ni = 0; ni < 4; ni++){
      int fl = ni*16 + lr;
      int tl = wv*32 + mi*16 + quad*4;
#pragma unroll
      for (int r = 0; r < 4; r++) Tr[fl*TSTR + tl + r] = f2bf(acc[mi][ni][r]);
    }
  __syncthreads();
  int f = tid >> 2, seg = tid & 3;
  int b_ = m0 >> 10;
  u16* dst = &WhT[(b_ * 512 + h * 64 + f) * NT + (m0 & 1023) + seg*32];
  const u16* srcp = &Tr[f*TSTR + seg*32];
#pragma unroll
  for (int k8 = 0; k8 < 4; k8++)
    *(bf16x8*)(dst + k8*8) = *(const bf16x8*)(srcp + k8*8);
}

// ---------- banded masked attention via MFMA + elu + signed-sqrt -> t2b (bf16)
//            + fused column sum-of-squares (atomicAdd into cn)
__launch_bounds__(256)
__global__ void k_attn(const u16* __restrict__ WhT, const float* __restrict__ es,
                       const float* __restrict__ ed, const int* __restrict__ sel,
                       u16* __restrict__ t2b, float* __restrict__ cn){
  __shared__ u16 P[64 * PSTR];
  __shared__ float edw[144];
  __shared__ int   selw[144];
  __shared__ float esw[64];
  __shared__ float swv[64];
  int bh = blockIdx.x;               // b*8+h
  int b = bh >> 3;
  int t0 = blockIdx.y * 64;
  int tid = threadIdx.x;
  int wv = tid >> 6, lane = tid & 63;
  int quad = lane >> 4, lr = lane & 15;
  int s_base = t0 - 40;
  for (int i = tid; i < 144; i += 256){
    int s = s_base + i;
    bool ok = (s >= 0 && s < NT);
    edw[i]  = ok ? ed[bh * NT + s] : 0.f;
    selw[i] = ok ? sel[b * NT + s] : 0;
  }
  if (tid < 64) esw[tid] = es[bh * NT + t0 + tid];
  {
    i32x4 z = {};
    for (int i = lane; i < 304; i += 64){
      int r16 = i / 19, c16 = i - r16 * 19;
      *(i32x4*)&P[(16*wv + r16) * PSTR + c16 * 8] = z;
    }
  }
  __syncthreads();
  {
    int tl = 16*wv + (lane >> 2);
    int q = lane & 3;
    float e_t = esw[tl];
    int sel_t = selw[tl + 40];
    float part = 0.f;
    for (int j = q; j <= 80; j += 4){
      int sw = tl + j;
      int s = s_base + sw;
      float w = 0.f;
      if (s >= 0 && s < NT && (sel_t | selw[sw])){
        float v = e_t + edw[sw];
        v = v > 0.f ? v : 0.2f * v;
        v = fminf(v, 60.f);
        w = bf2f(f2bf(__expf(v)));
      }
      part += w;
      if (w != 0.f) P[tl * PSTR + sw] = f2bf(w);
    }
    part += __shfl_xor(part, 1, 64);
    part += __shfl_xor(part, 2, 64);
    if (q == 0) swv[tl] = part;
  }
  f32x4 acc[4] = {};
  const u16* vbase = WhT + (bh * 64) * NT;
#pragma unroll
  for (int ks = 0; ks < 96; ks += 32){
    bf16x8 afr = *(const bf16x8*)&P[(16*wv + lr) * PSTR + 16*wv + ks + quad*8];
    int tb = s_base + 16*wv + ks + quad*8;
    bool ok = (tb >= 0) && (tb < NT);
    bf16x8 zf = {};
#pragma unroll
    for (int jn = 0; jn < 4; jn++){
      bf16x8 bfr = ok ? *(const bf16x8*)&vbase[(16*jn + lr) * NT + tb] : zf;
      acc[jn] = __builtin_amdgcn_mfma_f32_16x16x32_bf16(afr, bfr, acc[jn], 0, 0, 0);
    }
  }
#pragma unroll
  for (int jn = 0; jn < 4; jn++){
    float ssum = 0.f;
#pragma unroll
    for (int r = 0; r < 4; r++){
      int t_loc = 16*wv + quad*4 + r;
      float sw_ = swv[t_loc];
      float hp = acc[jn][r] / (sw_ > 0.f ? sw_ : 1.f);
      hp = hp > 0.f ? hp : (__expf(hp) - 1.f);
      float o = hp >= 0.f ? sqrtf(hp) : -sqrtf(-hp);
      ssum += o * o;
      t2b[(b * NT + t0 + t_loc) * ND + (bh & 7) * 64 + 16*jn + lr] = f2bf(o);
    }
    ssum += __shfl_xor(ssum, 16, 64);
    ssum += __shfl_xor(ssum, 32, 64);
    if (quad == 0) atomicAdd(&cn[b * ND + (bh & 7) * 64 + 16*jn + lr], ssum);
  }
}

// ---------- GEMM2: Y = (t2b*scl) @ W2 + x + b2 ; tile 128 x 64 ; fused LN partials
__launch_bounds__(256, 3)
__global__ void k_gemm2(const u16* __restrict__ A, const u16* __restrict__ Bt,
                        const float* __restrict__ xres, const float* __restrict__ b2,
                        const float* __restrict__ cn, float* __restrict__ Y,
                        float* __restrict__ rsum, float* __restrict__ rqsum){
  __shared__ u16 As[128 * 40];
  __shared__ u16 Bs[64 * 40];
  __shared__ float scl[512];
  int m0 = blockIdx.x * 128, n0 = blockIdx.y * 64;
  int tid = threadIdx.x;
  int wv = tid >> 6, lane = tid & 63;
  int quad = lane >> 4, lr = lane & 15;
  int bb0 = (m0 >> 10) << 9;          // b*512
  for (int i = tid; i < 512; i += 256){
    float nv = sqrtf(cn[bb0 + i]);
    scl[i] = 1.f / fmaxf(nv, 1e-12f);
  }
  f32x4 acc[2][4] = {};
  for (int kt = 0; kt < 512; kt += 32){
    __syncthreads();
#pragma unroll
    for (int i = 0; i < 2; i++){
      int e = tid * 8 + i * 2048;
      int r = e >> 5, c = e & 31;
      bf16x8 raw = *(const bf16x8*)&A[(m0 + r) * 512 + kt + c];
      u16 pk[8];
#pragma unroll
      for (int q = 0; q < 8; q++)
        pk[q] = f2bf(bf2f((u16)raw[q]) * scl[kt + c + q]);
      *(bf16x8*)&As[r*40 + c] = *(const bf16x8*)pk;
    }
    {
      int e = tid * 8;
      int r = e >> 5, c = e & 31;
      *(bf16x8*)&Bs[r*40 + c] = *(const bf16x8*)&Bt[(n0 + r) * 512 + kt + c];
    }
    __syncthreads();
    bf16x8 af[2], bfr[4];
#pragma unroll
    for (int i = 0; i < 2; i++) af[i] = *(const bf16x8*)&As[(wv*32 + i*16 + lr)*40 + quad*8];
#pragma unroll
    for (int i = 0; i < 4; i++) bfr[i] = *(const bf16x8*)&Bs[(i*16 + lr)*40 + quad*8];
#pragma unroll
    for (int mi = 0; mi < 2; mi++)
#pragma unroll
      for (int ni = 0; ni < 4; ni++)
        acc[mi][ni] = __builtin_amdgcn_mfma_f32_16x16x32_bf16(af[mi], bfr[ni], acc[mi][ni], 0, 0, 0);
  }
  float b2v[4];
#pragma unroll
  for (int ni = 0; ni < 4; ni++) b2v[ni] = b2[n0 + ni*16 + lr];
#pragma unroll
  for (int mi = 0; mi < 2; mi++){
    int rgb = m0 + wv*32 + mi*16 + quad*4;
#pragma unroll
    for (int r = 0; r < 4; r++){
      int row = rgb + r;
      float rs = 0.f, rq = 0.f;
#pragma unroll
      for (int ni = 0; ni < 4; ni++){
        int cg = n0 + ni*16 + lr;
        int idx = row * 512 + cg;
        float yv = acc[mi][ni][r] + xres[idx] + b2v[ni];
        Y[idx] = yv;
        rs += yv; rq += yv * yv;
      }
#pragma unroll
      for (int m2 = 1; m2 < 16; m2 <<= 1){
        rs += __shfl_xor(rs, m2, 64);
        rq += __shfl_xor(rq, m2, 64);
      }
      if (lr == 0){
        atomicAdd(&rsum[row], rs);
        atomicAdd(&rqsum[row], rq);
      }
    }
  }
}

// ---------- LN apply (stats precomputed) + transpose; block = 64 t x 128 d
__global__ void k_outln(const float* __restrict__ Y, const float* __restrict__ rsum,
                        const float* __restrict__ rqsum, const float* __restrict__ g,
                        const float* __restrict__ bb, float* __restrict__ out){
  __shared__ float mus[64], rss[64];
  __shared__ float tile[64 * 65];
  int t0 = blockIdx.x * 64, b = blockIdx.y;
  int cbase = blockIdx.z * 128;
  int tid = threadIdx.x;
  if (tid < 64){
    int row = b * NT + t0 + tid;
    float m = rsum[row] * (1.f/512.f);
    float var = rqsum[row] * (1.f/512.f) - m * m;
    mus[tid] = m;
    rss[tid] = 1.f / sqrtf(var + 1e-5f);
  }
  __syncthreads();
  int j = tid & 63, i0 = tid >> 6;
  for (int c0 = cbase; c0 < cbase + 128; c0 += 64){
#pragma unroll
    for (int k = 0; k < 16; k++){
      int i = i0 + k * 4;
      float v = (Y[(b * NT + t0 + i) * ND + c0 + j] - mus[i]) * rss[i] * g[c0 + j] + bb[c0 + j];
      tile[i * 65 + j] = v;
    }
    __syncthreads();
#pragma unroll
    for (int k = 0; k < 16; k++){
      int jj = i0 + k * 4;   // d-local
      out[(b * ND + c0 + jj) * NT + t0 + j] = tile[j * 65 + jj];
    }
    __syncthreads();
  }
}

extern "C" void kernel_launch(void* const* d_in, const int* in_sizes, int n_in,
                              void* d_out, int out_size, void* d_ws, size_t ws_size,
                              hipStream_t stream) {
  (void)in_sizes; (void)n_in; (void)out_size; (void)ws_size;
  const float* x     = (const float*)d_in[0];
  const float* W     = (const float*)d_in[1];
  const float* a_src = (const float*)d_in[2];
  const float* a_dst = (const float*)d_in[3];
  const float* W2    = (const float*)d_in[4];
  const float* b2    = (const float*)d_in[5];
  const float* ln_g  = (const float*)d_in[6];
  const float* ln_b  = (const float*)d_in[7];
  char* ws = (char*)d_ws;
  int*   sel   = (int*)  (ws + 256);
  float* mags  = (float*)(ws + 33024);
  u16*   WcatT = (u16*)  (ws + 65792);
  u16*   W2T   = (u16*)  (ws + 590080);
  float* es    = (float*)(ws + 1124608);
  float* ed    = (float*)(ws + 1386752);
  float* cn    = (float*)(ws + 1648896);   // 16 KB
  float* rsum  = (float*)(ws + 1665280);   // 32 KB
  float* rqsum = (float*)(ws + 1698048);   // 32 KB
  u16*   WhT   = (u16*)  (ws + 2097152);   // 8 MB; dead after k_attn
  u16*   t2b   = (u16*)  (ws + 18874368);  // 8 MB
  float* Y     = (float*)(ws + 2097152);   // 16 MB; overlays WhT after dead
  float* out   = (float*)d_out;

  k_convert_w<<<2048, 256, 0, stream>>>(W, W2, WcatT, W2T);
  hipMemsetAsync(cn, 0, 81920, stream);    // cn + rsum + rqsum
  k_gemm_wh  <<<dim3(64, 8), 256, 0, stream>>>(x, WcatT, a_src, a_dst, WhT, es, ed, mags);
  k_select   <<<dim3(NB, 16), 256, 0, stream>>>(mags, sel);
  k_attn     <<<dim3(64, 16), 256, 0, stream>>>(WhT, es, ed, sel, t2b, cn);
  k_gemm2    <<<dim3(64, 8), 256, 0, stream>>>(t2b, W2T, x, b2, cn, Y, rsum, rqsum);
  k_outln    <<<dim3(16, NB, 4), 256, 0, stream>>>(Y, rsum, rqsum, ln_g, ln_b, out);
}

// Round 10
// 160.023 us; speedup vs baseline: 2.2255x; 1.0137x over previous
//
#include <hip/hip_runtime.h>
#include <hip/hip_bf16.h>

typedef unsigned short u16;
typedef short bf16x8 __attribute__((ext_vector_type(8)));
typedef float f32x4 __attribute__((ext_vector_type(4)));
typedef int   i32x4 __attribute__((ext_vector_type(4)));

#define NB 8
#define NT 1024
#define ND 512
#define KSEL 307
#define PSTR 152   // attn P LDS row stride (elems)
#define TSTR 136   // gemm_wh transpose LDS row stride (elems)

__device__ __forceinline__ float bf2f(u16 u){
  union { unsigned int i; float f; } c; c.i = ((unsigned int)u) << 16; return c.f;
}
__device__ __forceinline__ u16 f2bf(float f){
  __hip_bfloat16 h = __float2bfloat16(f);
  u16 u; __builtin_memcpy(&u, &h, 2); return u;
}

// ---------- WcatT[c][d] = W[h=c>>6][d][f=c&63];  W2T[n][k] = W2[k][n]  (bf16)
__global__ void k_convert_w(const float* __restrict__ W, const float* __restrict__ W2,
                            u16* __restrict__ WcatT, u16* __restrict__ W2T){
  int idx = blockIdx.x * 256 + threadIdx.x;          // 0 .. 524287
  if (idx < 262144){
    int c = idx >> 9, d = idx & 511;
    int src = ((c >> 6) << 15) | (d << 6) | (c & 63);
    WcatT[idx] = f2bf(W[src]);
  } else {
    int i = idx - 262144;
    int n = i >> 9, k = i & 511;
    W2T[i] = f2bf(W2[(k << 9) | n]);
  }
}

// ---------- exact top-k selection by ranking; 4 threads per t, 64 t per block
__global__ void k_select(const float* __restrict__ mags, int* __restrict__ sel){
  __shared__ float sm[NT];
  int b = blockIdx.x;
  int tid = threadIdx.x;
  for (int i = tid; i < NT; i += 256) sm[i] = mags[b * NT + i];
  __syncthreads();
  int tl = tid >> 2, tq = tid & 3;
  int t = blockIdx.y * 64 + tl;
  float m = sm[t];
  int cnt = 0;
  int s0 = tq * 256;
  for (int s = s0; s < s0 + 256; s++){
    float v = sm[s];
    cnt += (v > m) || (v == m && s < t);
  }
  cnt += __shfl_xor(cnt, 1, 64);
  cnt += __shfl_xor(cnt, 2, 64);
  if (tq == 0) sel[b * NT + t] = (cnt < KSEL) ? 1 : 0;
}

// ---------- MFMA bf16 GEMM: Wh = bf16(x) @ Wcat ; tile 128(t) x 64(f = one head)
//   epilogue fuses: row mags (by==0), es/ed edge dots, transposed bf16 WhT write
__launch_bounds__(256, 3)
__global__ void k_gemm_wh(const float* __restrict__ x, const u16* __restrict__ Bt,
                          const float* __restrict__ a_src, const float* __restrict__ a_dst,
                          u16* __restrict__ WhT, float* __restrict__ es, float* __restrict__ ed,
                          float* __restrict__ mags){
  __shared__ u16 smem[8704];         // 17408 B; As(5120)+Bs(2560) alias Tr(64*TSTR)
  u16* As = smem;                    // 128 x 40
  u16* Bs = smem + 5120;             // 64 x 40
  int m0 = blockIdx.x * 128;         // t-block
  int h  = blockIdx.y;               // head (n0 = h*64)
  int tid = threadIdx.x;
  int wv = tid >> 6, lane = tid & 63;
  int quad = lane >> 4, lr = lane & 15;
  f32x4 acc[2][4] = {};
  float sq[2] = {0.f, 0.f};
  for (int kt = 0; kt < 512; kt += 32){
    __syncthreads();
#pragma unroll
    for (int i = 0; i < 2; i++){
      int e = tid * 8 + i * 2048;
      int r = e >> 5, c = e & 31;
      const float* xa = &x[(m0 + r) * 512 + kt + c];
      f32x4 u0 = *(const f32x4*)xa;
      f32x4 u1 = *(const f32x4*)(xa + 4);
      u16 pk[8];
#pragma unroll
      for (int q = 0; q < 4; q++){
        sq[i] += u0[q]*u0[q] + u1[q]*u1[q];
        pk[q] = f2bf(u0[q]); pk[4+q] = f2bf(u1[q]);
      }
      *(bf16x8*)&As[r*40 + c] = *(const bf16x8*)pk;
    }
    {
      int e = tid * 8;               // 0..2047 exactly covers 64x32
      int r = e >> 5, c = e & 31;
      *(bf16x8*)&Bs[r*40 + c] = *(const bf16x8*)&Bt[(h * 64 + r) * 512 + kt + c];
    }
    __syncthreads();
    bf16x8 af[2], bfr[4];
#pragma unroll
    for (int i = 0; i < 2; i++) af[i] = *(const bf16x8*)&As[(wv*32 + i*16 + lr)*40 + quad*8];
#pragma unroll
    for (int i = 0; i < 4; i++) bfr[i] = *(const bf16x8*)&Bs[(i*16 + lr)*40 + quad*8];
#pragma unroll
    for (int mi = 0; mi < 2; mi++)
#pragma unroll
      for (int ni = 0; ni < 4; ni++)
        acc[mi][ni] = __builtin_amdgcn_mfma_f32_16x16x32_bf16(af[mi], bfr[ni], acc[mi][ni], 0, 0, 0);
  }
  // ---- epilogue 0: row L2 norms (4 lanes per row)
  if (blockIdx.y == 0){
#pragma unroll
    for (int i = 0; i < 2; i++){
      float s = sq[i];
      s += __shfl_xor(s, 1, 64);
      s += __shfl_xor(s, 2, 64);
      if ((tid & 3) == 0) mags[m0 + i*64 + (tid >> 2)] = sqrtf(s);
    }
  }
  // ---- epilogue 1: edge dot products (wave owns rows wv*32..+32, full head width)
  float asv[4], adv[4];
#pragma unroll
  for (int ni = 0; ni < 4; ni++){
    asv[ni] = a_src[h*64 + ni*16 + lr];
    adv[ni] = a_dst[h*64 + ni*16 + lr];
  }
#pragma unroll
  for (int mi = 0; mi < 2; mi++)
#pragma unroll
    for (int r = 0; r < 4; r++){
      float pes = 0.f, ped = 0.f;
#pragma unroll
      for (int ni = 0; ni < 4; ni++){
        pes += acc[mi][ni][r] * asv[ni];
        ped += acc[mi][ni][r] * adv[ni];
      }
#pragma unroll
      for (int mofs = 1; mofs < 16; mofs <<= 1){
        pes += __shfl_xor(pes, mofs, 64);
        ped += __shfl_xor(ped, mofs, 64);
      }
      if (lr == 0){
        int rowg = m0 + wv*32 + mi*16 + quad*4 + r;
        int bb_ = rowg >> 10, tt = rowg & 1023;
        es[(bb_ * 8 + h) * NT + tt] = pes;
        ed[(bb_ * 8 + h) * NT + tt] = ped;
      }
    }
  // ---- epilogue 2: bf16 transpose via LDS -> WhT[(b*512 + h*64 + f)][t]
  __syncthreads();
  u16* Tr = smem;   // [f][t], stride TSTR
#pragma unroll
  for (int mi = 0; mi < 2; mi++)
#pragma unroll
    for (int ni = 0; ni < 4; ni++){
      int fl = ni*16 + lr;
      int tl = wv*32 + mi*16 + quad*4;
#pragma unroll
      for (int r = 0; r < 4; r++) Tr[fl*TSTR + tl + r] = f2bf(acc[mi][ni][r]);
    }
  __syncthreads();
  int f = tid >> 2, seg = tid & 3;
  int b_ = m0 >> 10;
  u16* dst = &WhT[(b_ * 512 + h * 64 + f) * NT + (m0 & 1023) + seg*32];
  const u16* srcp = &Tr[f*TSTR + seg*32];
#pragma unroll
  for (int k8 = 0; k8 < 4; k8++)
    *(bf16x8*)(dst + k8*8) = *(const bf16x8*)(srcp + k8*8);
}

// ---------- banded masked attention via MFMA + elu + signed-sqrt -> t2b (bf16)
//            + fused column sum-of-squares (atomicAdd into cn)
__launch_bounds__(256)
__global__ void k_attn(const u16* __restrict__ WhT, const float* __restrict__ es,
                       const float* __restrict__ ed, const int* __restrict__ sel,
                       u16* __restrict__ t2b, float* __restrict__ cn){
  __shared__ u16 P[64 * PSTR];
  __shared__ float edw[144];
  __shared__ int   selw[144];
  __shared__ float esw[64];
  __shared__ float swv[64];
  int bh = blockIdx.x;               // b*8+h
  int b = bh >> 3;
  int t0 = blockIdx.y * 64;
  int tid = threadIdx.x;
  int wv = tid >> 6, lane = tid & 63;
  int quad = lane >> 4, lr = lane & 15;
  int s_base = t0 - 40;
  for (int i = tid; i < 144; i += 256){
    int s = s_base + i;
    bool ok = (s >= 0 && s < NT);
    edw[i]  = ok ? ed[bh * NT + s] : 0.f;
    selw[i] = ok ? sel[b * NT + s] : 0;
  }
  if (tid < 64) esw[tid] = es[bh * NT + t0 + tid];
  {
    i32x4 z = {};
    for (int i = lane; i < 304; i += 64){
      int r16 = i / 19, c16 = i - r16 * 19;
      *(i32x4*)&P[(16*wv + r16) * PSTR + c16 * 8] = z;
    }
  }
  __syncthreads();
  {
    int tl = 16*wv + (lane >> 2);
    int q = lane & 3;
    float e_t = esw[tl];
    int sel_t = selw[tl + 40];
    float part = 0.f;
    for (int j = q; j <= 80; j += 4){
      int sw = tl + j;
      int s = s_base + sw;
      float w = 0.f;
      if (s >= 0 && s < NT && (sel_t | selw[sw])){
        float v = e_t + edw[sw];
        v = v > 0.f ? v : 0.2f * v;
        v = fminf(v, 60.f);
        w = bf2f(f2bf(__expf(v)));
      }
      part += w;
      if (w != 0.f) P[tl * PSTR + sw] = f2bf(w);
    }
    part += __shfl_xor(part, 1, 64);
    part += __shfl_xor(part, 2, 64);
    if (q == 0) swv[tl] = part;
  }
  f32x4 acc[4] = {};
  const u16* vbase = WhT + (bh * 64) * NT;
#pragma unroll
  for (int ks = 0; ks < 96; ks += 32){
    bf16x8 afr = *(const bf16x8*)&P[(16*wv + lr) * PSTR + 16*wv + ks + quad*8];
    int tb = s_base + 16*wv + ks + quad*8;
    bool ok = (tb >= 0) && (tb < NT);
    bf16x8 zf = {};
#pragma unroll
    for (int jn = 0; jn < 4; jn++){
      bf16x8 bfr = ok ? *(const bf16x8*)&vbase[(16*jn + lr) * NT + tb] : zf;
      acc[jn] = __builtin_amdgcn_mfma_f32_16x16x32_bf16(afr, bfr, acc[jn], 0, 0, 0);
    }
  }
#pragma unroll
  for (int jn = 0; jn < 4; jn++){
    float ssum = 0.f;
#pragma unroll
    for (int r = 0; r < 4; r++){
      int t_loc = 16*wv + quad*4 + r;
      float sw_ = swv[t_loc];
      float hp = acc[jn][r] / (sw_ > 0.f ? sw_ : 1.f);
      hp = hp > 0.f ? hp : (__expf(hp) - 1.f);
      float o = hp >= 0.f ? sqrtf(hp) : -sqrtf(-hp);
      ssum += o * o;
      t2b[(b * NT + t0 + t_loc) * ND + (bh & 7) * 64 + 16*jn + lr] = f2bf(o);
    }
    ssum += __shfl_xor(ssum, 16, 64);
    ssum += __shfl_xor(ssum, 32, 64);
    if (quad == 0) atomicAdd(&cn[b * ND + (bh & 7) * 64 + 16*jn + lr], ssum);
  }
}

// ---------- GEMM2: Y = (t2b*scl) @ W2 + x + b2 ; tile 128 x 64 ; fused LN partials
__launch_bounds__(256, 3)
__global__ void k_gemm2(const u16* __restrict__ A, const u16* __restrict__ Bt,
                        const float* __restrict__ xres, const float* __restrict__ b2,
                        const float* __restrict__ cn, float* __restrict__ Y,
                        float* __restrict__ rsum, float* __restrict__ rqsum){
  __shared__ u16 As[128 * 40];
  __shared__ u16 Bs[64 * 40];
  __shared__ float scl[512];
  int m0 = blockIdx.x * 128, n0 = blockIdx.y * 64;
  int tid = threadIdx.x;
  int wv = tid >> 6, lane = tid & 63;
  int quad = lane >> 4, lr = lane & 15;
  int bb0 = (m0 >> 10) << 9;          // b*512
  for (int i = tid; i < 512; i += 256){
    float nv = sqrtf(cn[bb0 + i]);
    scl[i] = 1.f / fmaxf(nv, 1e-12f);
  }
  f32x4 acc[2][4] = {};
  for (int kt = 0; kt < 512; kt += 32){
    __syncthreads();
#pragma unroll
    for (int i = 0; i < 2; i++){
      int e = tid * 8 + i * 2048;
      int r = e >> 5, c = e & 31;
      bf16x8 raw = *(const bf16x8*)&A[(m0 + r) * 512 + kt + c];
      u16 pk[8];
#pragma unroll
      for (int q = 0; q < 8; q++)
        pk[q] = f2bf(bf2f((u16)raw[q]) * scl[kt + c + q]);
      *(bf16x8*)&As[r*40 + c] = *(const bf16x8*)pk;
    }
    {
      int e = tid * 8;
      int r = e >> 5, c = e & 31;
      *(bf16x8*)&Bs[r*40 + c] = *(const bf16x8*)&Bt[(n0 + r) * 512 + kt + c];
    }
    __syncthreads();
    bf16x8 af[2], bfr[4];
#pragma unroll
    for (int i = 0; i < 2; i++) af[i] = *(const bf16x8*)&As[(wv*32 + i*16 + lr)*40 + quad*8];
#pragma unroll
    for (int i = 0; i < 4; i++) bfr[i] = *(const bf16x8*)&Bs[(i*16 + lr)*40 + quad*8];
#pragma unroll
    for (int mi = 0; mi < 2; mi++)
#pragma unroll
      for (int ni = 0; ni < 4; ni++)
        acc[mi][ni] = __builtin_amdgcn_mfma_f32_16x16x32_bf16(af[mi], bfr[ni], acc[mi][ni], 0, 0, 0);
  }
  float b2v[4];
#pragma unroll
  for (int ni = 0; ni < 4; ni++) b2v[ni] = b2[n0 + ni*16 + lr];
#pragma unroll
  for (int mi = 0; mi < 2; mi++){
    int rgb = m0 + wv*32 + mi*16 + quad*4;
#pragma unroll
    for (int r = 0; r < 4; r++){
      int row = rgb + r;
      float rs = 0.f, rq = 0.f;
#pragma unroll
      for (int ni = 0; ni < 4; ni++){
        int cg = n0 + ni*16 + lr;
        int idx = row * 512 + cg;
        float yv = acc[mi][ni][r] + xres[idx] + b2v[ni];
        Y[idx] = yv;
        rs += yv; rq += yv * yv;
      }
#pragma unroll
      for (int m2 = 1; m2 < 16; m2 <<= 1){
        rs += __shfl_xor(rs, m2, 64);
        rq += __shfl_xor(rq, m2, 64);
      }
      if (lr == 0){
        atomicAdd(&rsum[row], rs);
        atomicAdd(&rqsum[row], rq);
      }
    }
  }
}

// ---------- LN apply (stats precomputed) + transpose; block = 64 t x 128 d
__global__ void k_outln(const float* __restrict__ Y, const float* __restrict__ rsum,
                        const float* __restrict__ rqsum, const float* __restrict__ g,
                        const float* __restrict__ bb, float* __restrict__ out){
  __shared__ float mus[64], rss[64];
  __shared__ float tile[64 * 65];
  int t0 = blockIdx.x * 64, b = blockIdx.y;
  int cbase = blockIdx.z * 128;
  int tid = threadIdx.x;
  if (tid < 64){
    int row = b * NT + t0 + tid;
    float m = rsum[row] * (1.f/512.f);
    float var = rqsum[row] * (1.f/512.f) - m * m;
    mus[tid] = m;
    rss[tid] = 1.f / sqrtf(var + 1e-5f);
  }
  __syncthreads();
  int j = tid & 63, i0 = tid >> 6;
  for (int c0 = cbase; c0 < cbase + 128; c0 += 64){
#pragma unroll
    for (int k = 0; k < 16; k++){
      int i = i0 + k * 4;
      float v = (Y[(b * NT + t0 + i) * ND + c0 + j] - mus[i]) * rss[i] * g[c0 + j] + bb[c0 + j];
      tile[i * 65 + j] = v;
    }
    __syncthreads();
#pragma unroll
    for (int k = 0; k < 16; k++){
      int jj = i0 + k * 4;   // d-local
      out[(b * ND + c0 + jj) * NT + t0 + j] = tile[j * 65 + jj];
    }
    __syncthreads();
  }
}

extern "C" void kernel_launch(void* const* d_in, const int* in_sizes, int n_in,
                              void* d_out, int out_size, void* d_ws, size_t ws_size,
                              hipStream_t stream) {
  (void)in_sizes; (void)n_in; (void)out_size; (void)ws_size;
  const float* x     = (const float*)d_in[0];
  const float* W     = (const float*)d_in[1];
  const float* a_src = (const float*)d_in[2];
  const float* a_dst = (const float*)d_in[3];
  const float* W2    = (const float*)d_in[4];
  const float* b2    = (const float*)d_in[5];
  const float* ln_g  = (const float*)d_in[6];
  const float* ln_b  = (const float*)d_in[7];
  char* ws = (char*)d_ws;
  int*   sel   = (int*)  (ws + 256);
  float* mags  = (float*)(ws + 33024);
  u16*   WcatT = (u16*)  (ws + 65792);
  u16*   W2T   = (u16*)  (ws + 590080);
  float* es    = (float*)(ws + 1124608);
  float* ed    = (float*)(ws + 1386752);
  float* cn    = (float*)(ws + 1648896);   // 16 KB
  float* rsum  = (float*)(ws + 1665280);   // 32 KB
  float* rqsum = (float*)(ws + 1698048);   // 32 KB
  u16*   WhT   = (u16*)  (ws + 2097152);   // 8 MB; dead after k_attn
  u16*   t2b   = (u16*)  (ws + 18874368);  // 8 MB
  float* Y     = (float*)(ws + 2097152);   // 16 MB; overlays WhT after dead
  float* out   = (float*)d_out;

  k_convert_w<<<2048, 256, 0, stream>>>(W, W2, WcatT, W2T);
  hipMemsetAsync(cn, 0, 81920, stream);    // cn + rsum + rqsum
  k_gemm_wh  <<<dim3(64, 8), 256, 0, stream>>>(x, WcatT, a_src, a_dst, WhT, es, ed, mags);
  k_select   <<<dim3(NB, 16), 256, 0, stream>>>(mags, sel);
  k_attn     <<<dim3(64, 16), 256, 0, stream>>>(WhT, es, ed, sel, t2b, cn);
  k_gemm2    <<<dim3(64, 8), 256, 0, stream>>>(t2b, W2T, x, b2, cn, Y, rsum, rqsum);
  k_outln    <<<dim3(16, NB, 4), 256, 0, stream>>>(Y, rsum, rqsum, ln_g, ln_b, out);
}